// Round 2
// baseline (982.779 us; speedup 1.0000x reference)
//
#include <hip/hip_runtime.h>

#define N_NODES 100000
#define EDGES   1600000
#define EMB     64
#define H1      128
#define H2      64

// workspace layout (in 4-byte elements)
#define OFF_DEG   0
#define OFF_DINV  100000
#define OFF_ROWP  200000      // N+1 entries, padded
#define OFF_FILL  300004
#define OFF_COL   400004
#define OFF_H     2000004     // N*128 floats (layer1 pre-agg; reused as h2 N*64)
#define OFF_Y     14800004    // N*128 floats (layer1 post-relu)
#define OFF_BSUM  27600004    // scan block sums

// ---------------- degree / dinv ----------------

__global__ void k_deg(const int* __restrict__ dst, int E, int* __restrict__ deg) {
    int i = blockIdx.x * blockDim.x + threadIdx.x;
    int stride = gridDim.x * blockDim.x;
    for (; i < E; i += stride) atomicAdd(&deg[dst[i]], 1);
}

__global__ void k_dinv(const int* __restrict__ deg, float* __restrict__ dinv, int N) {
    int i = blockIdx.x * blockDim.x + threadIdx.x;
    if (i < N) dinv[i] = rsqrtf((float)(deg[i] + 1));   // +1 self-loop
}

// ---------------- exclusive scan (3-kernel) ----------------
// 1024 elements per block (256 threads x 4)

__global__ void k_scan1(const int* __restrict__ deg, int N,
                        int* __restrict__ rowp, int* __restrict__ bsum) {
    __shared__ int sh[256];
    int b = blockIdx.x, t = threadIdx.x;
    int base = b * 1024 + t * 4;
    int v0 = (base + 0 < N) ? deg[base + 0] : 0;
    int v1 = (base + 1 < N) ? deg[base + 1] : 0;
    int v2 = (base + 2 < N) ? deg[base + 2] : 0;
    int v3 = (base + 3 < N) ? deg[base + 3] : 0;
    sh[t] = v0 + v1 + v2 + v3;
    __syncthreads();
    for (int off = 1; off < 256; off <<= 1) {
        int x = (t >= off) ? sh[t - off] : 0;
        __syncthreads();
        sh[t] += x;
        __syncthreads();
    }
    if (t == 255) bsum[b] = sh[255];
    int run = (t == 0) ? 0 : sh[t - 1];
    if (base + 0 < N) rowp[base + 0] = run; run += v0;
    if (base + 1 < N) rowp[base + 1] = run; run += v1;
    if (base + 2 < N) rowp[base + 2] = run; run += v2;
    if (base + 3 < N) rowp[base + 3] = run;
}

__global__ void k_scan2(int* __restrict__ bsum, int nb) {
    __shared__ int sh[256];
    int t = threadIdx.x;
    sh[t] = (t < nb) ? bsum[t] : 0;
    __syncthreads();
    for (int off = 1; off < 256; off <<= 1) {
        int x = (t >= off) ? sh[t - off] : 0;
        __syncthreads();
        sh[t] += x;
        __syncthreads();
    }
    int excl = (t == 0) ? 0 : sh[t - 1];
    if (t < nb) bsum[t] = excl;
}

__global__ void k_scan3(int* __restrict__ rowp, const int* __restrict__ bsum,
                        int N, int E, int* __restrict__ fill) {
    int b = blockIdx.x, t = threadIdx.x;
    int base = b * 1024 + t * 4;
    int add = bsum[b];
    #pragma unroll
    for (int u = 0; u < 4; ++u) {
        int i = base + u;
        if (i < N) { int r = rowp[i] + add; rowp[i] = r; fill[i] = r; }
    }
    if (b == 0 && t == 0) rowp[N] = E;
}

__global__ void k_scatter(const int* __restrict__ src, const int* __restrict__ dst, int E,
                          int* __restrict__ fill, int* __restrict__ col) {
    int i = blockIdx.x * blockDim.x + threadIdx.x;
    int stride = gridDim.x * blockDim.x;
    for (; i < E; i += stride) {
        int d = dst[i];
        int pos = atomicAdd(&fill[d], 1);
        col[pos] = src[i];
    }
}

// ---------------- layer 1 GEMM: x(emb concat)[N,192] @ W1[192,128] ----------------
// j-split: each block owns 64 of the 128 output cols (48KB W half in LDS).
// 16 nodes per tile; 4 groups of 64 threads; each thread: 4 nodes x 1 col.

__global__ __launch_bounds__(256) void k_gemm1(
    const int* __restrict__ cid, const int* __restrict__ sid, const int* __restrict__ eid,
    const float* __restrict__ cat_t, const float* __restrict__ sub_t,
    const float* __restrict__ elem_t, const float* __restrict__ W1,
    float* __restrict__ h, int N)
{
    __shared__ float Wl[192 * 64];
    __shared__ float xl[16][192];
    int bid = blockIdx.x;
    int jhalf = bid & 1;
    int t = threadIdx.x;

    // stage W1 half-columns [jhalf*64, jhalf*64+64)
    for (int idx = t; idx < 192 * 64; idx += 256) {
        int k = idx >> 6, j = idx & 63;
        Wl[idx] = W1[k * 128 + jhalf * 64 + j];
    }

    int j = t & 63, g = t >> 6;           // 4 groups, 4 nodes each
    int ntiles = (N + 15) >> 4;
    int tstride = gridDim.x >> 1;
    for (int tile = bid >> 1; tile < ntiles; tile += tstride) {
        int n0 = tile << 4;
        __syncthreads();                  // xl reuse barrier (also covers Wl on iter 0)
        for (int idx = t; idx < 16 * 192; idx += 256) {
            int ln = idx / 192, c = idx - ln * 192;
            int n = n0 + ln;
            float v = 0.f;
            if (n < N) {
                if (c < 64)        v = cat_t[cid[n] * 64 + c];
                else if (c < 128)  v = sub_t[sid[n] * 64 + (c - 64)];
                else               v = elem_t[eid[n] * 64 + (c - 128)];
            }
            xl[ln][c] = v;
        }
        __syncthreads();

        const float* x0 = xl[g * 4 + 0];
        const float* x1 = xl[g * 4 + 1];
        const float* x2 = xl[g * 4 + 2];
        const float* x3 = xl[g * 4 + 3];
        float a0 = 0.f, a1 = 0.f, a2 = 0.f, a3 = 0.f;
        #pragma unroll 16
        for (int k = 0; k < 192; ++k) {
            float w = Wl[k * 64 + j];
            a0 += w * x0[k];
            a1 += w * x1[k];
            a2 += w * x2[k];
            a3 += w * x3[k];
        }
        int n = n0 + g * 4;
        int jj = jhalf * 64 + j;
        if (n + 0 < N) h[(n + 0) * 128 + jj] = a0;
        if (n + 1 < N) h[(n + 1) * 128 + jj] = a1;
        if (n + 2 < N) h[(n + 2) * 128 + jj] = a2;
        if (n + 3 < N) h[(n + 3) * 128 + jj] = a3;
    }
}

// ---------------- layer 1 aggregation (gather-side, CSR) ----------------
// 128 threads per dst node, 2 nodes per block.

__global__ __launch_bounds__(256) void k_agg1(
    const float* __restrict__ h, const int* __restrict__ rowp, const int* __restrict__ col,
    const float* __restrict__ dinv, const float* __restrict__ b1,
    float* __restrict__ y, int N)
{
    int g = threadIdx.x >> 7;
    int j = threadIdx.x & 127;
    int d = blockIdx.x * 2 + g;
    if (d >= N) return;
    float dd = dinv[d];
    float acc = h[d * 128 + j] * (dd * dd);     // self-loop
    int e = rowp[d], e1 = rowp[d + 1];
    while (e + 1 < e1) {
        int s0 = col[e], s1 = col[e + 1];
        float w0 = dinv[s0] * dd, w1 = dinv[s1] * dd;
        acc += h[s0 * 128 + j] * w0;
        acc += h[s1 * 128 + j] * w1;
        e += 2;
    }
    if (e < e1) {
        int s = col[e];
        acc += h[s * 128 + j] * (dinv[s] * dd);
    }
    float v = acc + b1[j];
    y[d * 128 + j] = v > 0.f ? v : 0.f;
}

// ---------------- layer 2 GEMM: y[N,128] @ W2[128,64] ----------------

__global__ __launch_bounds__(256) void k_gemm2(
    const float* __restrict__ y, const float* __restrict__ W2,
    float* __restrict__ h2, int N)
{
    __shared__ float Wl[128 * 64];
    __shared__ float xl[16][128];
    int t = threadIdx.x;
    for (int idx = t; idx < 128 * 64; idx += 256) Wl[idx] = W2[idx];

    int j = t & 63, g = t >> 6;
    int ntiles = (N + 15) >> 4;
    for (int tile = blockIdx.x; tile < ntiles; tile += gridDim.x) {
        int n0 = tile << 4;
        __syncthreads();
        for (int idx = t; idx < 16 * 128; idx += 256) {
            int ln = idx >> 7, c = idx & 127;
            int n = n0 + ln;
            xl[ln][c] = (n < N) ? y[n * 128 + c] : 0.f;
        }
        __syncthreads();

        const float* x0 = xl[g * 4 + 0];
        const float* x1 = xl[g * 4 + 1];
        const float* x2 = xl[g * 4 + 2];
        const float* x3 = xl[g * 4 + 3];
        float a0 = 0.f, a1 = 0.f, a2 = 0.f, a3 = 0.f;
        #pragma unroll 16
        for (int k = 0; k < 128; ++k) {
            float w = Wl[k * 64 + j];
            a0 += w * x0[k];
            a1 += w * x1[k];
            a2 += w * x2[k];
            a3 += w * x3[k];
        }
        int n = n0 + g * 4;
        if (n + 0 < N) h2[(n + 0) * 64 + j] = a0;
        if (n + 1 < N) h2[(n + 1) * 64 + j] = a1;
        if (n + 2 < N) h2[(n + 2) * 64 + j] = a2;
        if (n + 3 < N) h2[(n + 3) * 64 + j] = a3;
    }
}

// ---------------- layer 2 aggregation → output ----------------
// 64 threads per dst node, 4 nodes per block.

__global__ __launch_bounds__(256) void k_agg2(
    const float* __restrict__ h2, const int* __restrict__ rowp, const int* __restrict__ col,
    const float* __restrict__ dinv, const float* __restrict__ b2,
    float* __restrict__ out, int N)
{
    int g = threadIdx.x >> 6;
    int j = threadIdx.x & 63;
    int d = blockIdx.x * 4 + g;
    if (d >= N) return;
    float dd = dinv[d];
    float acc = h2[d * 64 + j] * (dd * dd);
    int e = rowp[d], e1 = rowp[d + 1];
    while (e + 1 < e1) {
        int s0 = col[e], s1 = col[e + 1];
        float w0 = dinv[s0] * dd, w1 = dinv[s1] * dd;
        acc += h2[s0 * 64 + j] * w0;
        acc += h2[s1 * 64 + j] * w1;
        e += 2;
    }
    if (e < e1) {
        int s = col[e];
        acc += h2[s * 64 + j] * (dinv[s] * dd);
    }
    float v = acc + b2[j];
    out[d * 64 + j] = v > 0.f ? v : 0.f;
}

// ---------------- launch ----------------

extern "C" void kernel_launch(void* const* d_in, const int* in_sizes, int n_in,
                              void* d_out, int out_size, void* d_ws, size_t ws_size,
                              hipStream_t stream) {
    const int*   cid    = (const int*)d_in[0];
    const int*   sid    = (const int*)d_in[1];
    const int*   eid    = (const int*)d_in[2];
    const int*   edge   = (const int*)d_in[3];
    const float* cat_t  = (const float*)d_in[4];
    const float* sub_t  = (const float*)d_in[5];
    const float* elem_t = (const float*)d_in[6];
    const float* W1     = (const float*)d_in[7];
    const float* b1     = (const float*)d_in[8];
    const float* W2     = (const float*)d_in[9];
    const float* b2     = (const float*)d_in[10];
    float* out = (float*)d_out;

    int N = in_sizes[0];
    int E = in_sizes[3] / 2;
    const int* src = edge;
    const int* dst = edge + E;

    int*   ws   = (int*)d_ws;
    int*   deg  = ws + OFF_DEG;
    float* dinv = (float*)(ws + OFF_DINV);
    int*   rowp = ws + OFF_ROWP;
    int*   fill = ws + OFF_FILL;
    int*   col  = ws + OFF_COL;
    float* h    = (float*)(ws + OFF_H);
    float* y    = (float*)(ws + OFF_Y);
    int*   bsum = ws + OFF_BSUM;

    hipMemsetAsync(deg, 0, (size_t)N * sizeof(int), stream);

    k_deg<<<2048, 256, 0, stream>>>(dst, E, deg);
    k_dinv<<<(N + 255) / 256, 256, 0, stream>>>(deg, dinv, N);

    int nb = (N + 1023) / 1024;          // 98 blocks
    k_scan1<<<nb, 256, 0, stream>>>(deg, N, rowp, bsum);
    k_scan2<<<1, 256, 0, stream>>>(bsum, nb);
    k_scan3<<<nb, 256, 0, stream>>>(rowp, bsum, N, E, fill);
    k_scatter<<<2048, 256, 0, stream>>>(src, dst, E, fill, col);

    k_gemm1<<<512, 256, 0, stream>>>(cid, sid, eid, cat_t, sub_t, elem_t, W1, h, N);
    k_agg1<<<(N + 1) / 2, 256, 0, stream>>>(h, rowp, col, dinv, b1, y, N);
    k_gemm2<<<1024, 256, 0, stream>>>(y, W2, h, N);      // h reused as h2
    k_agg2<<<(N + 3) / 4, 256, 0, stream>>>(h, rowp, col, dinv, b2, out, N);
}

// Round 3
// 677.000 us; speedup vs baseline: 1.4517x; 1.4517x over previous
//
#include <hip/hip_runtime.h>

#define N_NODES 100000
#define EMB     64
#define H1      128
#define H2      64

// workspace layout (in 4-byte elements) — unchanged from round 0 (<=110.4MB proven ok)
#define OFF_DEG   0
#define OFF_DINV  100000
#define OFF_ROWP  200000      // N+1 entries, padded
#define OFF_FILL  300004
#define OFF_COL   400004
#define OFF_H     2000004     // N*128 floats (layer1 pre-agg; reused as h2 N*64)
#define OFF_Y     14800004    // N*128 floats (layer1 post-relu)
#define OFF_BSUM  27600004    // scan block sums

// ---------------- degree / dinv ----------------

__global__ void k_deg(const int* __restrict__ dst, int E, int* __restrict__ deg) {
    int i = blockIdx.x * blockDim.x + threadIdx.x;
    int stride = gridDim.x * blockDim.x;
    for (; i < E; i += stride) atomicAdd(&deg[dst[i]], 1);
}

__global__ void k_dinv(const int* __restrict__ deg, float* __restrict__ dinv, int N) {
    int i = blockIdx.x * blockDim.x + threadIdx.x;
    if (i < N) dinv[i] = rsqrtf((float)(deg[i] + 1));   // +1 self-loop
}

// ---------------- exclusive scan (3-kernel) ----------------

__global__ void k_scan1(const int* __restrict__ deg, int N,
                        int* __restrict__ rowp, int* __restrict__ bsum) {
    __shared__ int sh[256];
    int b = blockIdx.x, t = threadIdx.x;
    int base = b * 1024 + t * 4;
    int v0 = (base + 0 < N) ? deg[base + 0] : 0;
    int v1 = (base + 1 < N) ? deg[base + 1] : 0;
    int v2 = (base + 2 < N) ? deg[base + 2] : 0;
    int v3 = (base + 3 < N) ? deg[base + 3] : 0;
    sh[t] = v0 + v1 + v2 + v3;
    __syncthreads();
    for (int off = 1; off < 256; off <<= 1) {
        int x = (t >= off) ? sh[t - off] : 0;
        __syncthreads();
        sh[t] += x;
        __syncthreads();
    }
    if (t == 255) bsum[b] = sh[255];
    int run = (t == 0) ? 0 : sh[t - 1];
    if (base + 0 < N) rowp[base + 0] = run; run += v0;
    if (base + 1 < N) rowp[base + 1] = run; run += v1;
    if (base + 2 < N) rowp[base + 2] = run; run += v2;
    if (base + 3 < N) rowp[base + 3] = run;
}

__global__ void k_scan2(int* __restrict__ bsum, int nb) {
    __shared__ int sh[256];
    int t = threadIdx.x;
    sh[t] = (t < nb) ? bsum[t] : 0;
    __syncthreads();
    for (int off = 1; off < 256; off <<= 1) {
        int x = (t >= off) ? sh[t - off] : 0;
        __syncthreads();
        sh[t] += x;
        __syncthreads();
    }
    int excl = (t == 0) ? 0 : sh[t - 1];
    if (t < nb) bsum[t] = excl;
}

__global__ void k_scan3(int* __restrict__ rowp, const int* __restrict__ bsum,
                        int N, int E, int* __restrict__ fill) {
    int b = blockIdx.x, t = threadIdx.x;
    int base = b * 1024 + t * 4;
    int add = bsum[b];
    #pragma unroll
    for (int u = 0; u < 4; ++u) {
        int i = base + u;
        if (i < N) { int r = rowp[i] + add; rowp[i] = r; fill[i] = r; }
    }
    if (b == 0 && t == 0) rowp[N] = E;
}

__global__ void k_scatter(const int* __restrict__ src, const int* __restrict__ dst, int E,
                          int* __restrict__ fill, int* __restrict__ col) {
    int i = blockIdx.x * blockDim.x + threadIdx.x;
    int stride = gridDim.x * blockDim.x;
    for (; i < E; i += stride) {
        int d = dst[i];
        int pos = atomicAdd(&fill[d], 1);
        col[pos] = src[i];
    }
}

// ---------------- layer 1 GEMM: x(emb concat)[N,192] @ W1[192,128] ----------------
// W half (192x64, 48KB) in LDS staged ONCE; x read direct from tables (L1/L2
// broadcast: 16 lanes share each address). Thread: 8 nodes x 4 cols = 32 acc.
// Per 4 k's: 8 VMEM b128 + 4 LDS b128 + 128 FMA. No barriers in main loop.

__global__ __launch_bounds__(256) void k_gemm1(
    const int* __restrict__ cid, const int* __restrict__ sid, const int* __restrict__ eid,
    const float* __restrict__ cat_t, const float* __restrict__ sub_t,
    const float* __restrict__ elem_t, const float* __restrict__ W1,
    float* __restrict__ h, int N)
{
    __shared__ float Wl[192][64];           // 48KB -> 3 blocks/CU
    int t = threadIdx.x;
    int jh = blockIdx.x & 1;
    for (int idx = t; idx < 192 * 64; idx += 256) {
        int k = idx >> 6, j = idx & 63;
        Wl[k][j] = W1[k * 128 + jh * 64 + j];
    }
    __syncthreads();

    int cg = t & 15;          // 4 cols: cg*4..+3 (within the 64-col half)
    int ng = t >> 4;          // 8 nodes: n0 + ng + 16*i
    int ntiles = (N + 127) >> 7;
    int tstride = gridDim.x >> 1;
    for (int tile = blockIdx.x >> 1; tile < ntiles; tile += tstride) {
        int n0 = tile << 7;
        float4 acc[8];
        #pragma unroll
        for (int i = 0; i < 8; ++i) acc[i] = make_float4(0.f, 0.f, 0.f, 0.f);

        #pragma unroll
        for (int seg = 0; seg < 3; ++seg) {
            const float* tab = (seg == 0) ? cat_t : (seg == 1) ? sub_t : elem_t;
            const int*   ids = (seg == 0) ? cid   : (seg == 1) ? sid   : eid;
            const float* rp[8];
            #pragma unroll
            for (int i = 0; i < 8; ++i) {
                int n = n0 + ng + 16 * i;
                int id = ids[(n < N) ? n : 0];
                rp[i] = tab + (size_t)id * 64;
            }
            #pragma unroll 4
            for (int k4 = 0; k4 < 16; ++k4) {
                float4 xv[8];
                #pragma unroll
                for (int i = 0; i < 8; ++i)
                    xv[i] = *(const float4*)(rp[i] + k4 * 4);
                #pragma unroll
                for (int kk = 0; kk < 4; ++kk) {
                    float4 w = *(const float4*)&Wl[seg * 64 + k4 * 4 + kk][cg * 4];
                    #pragma unroll
                    for (int i = 0; i < 8; ++i) {
                        float xx = (kk == 0) ? xv[i].x : (kk == 1) ? xv[i].y
                                 : (kk == 2) ? xv[i].z : xv[i].w;
                        acc[i].x += xx * w.x;
                        acc[i].y += xx * w.y;
                        acc[i].z += xx * w.z;
                        acc[i].w += xx * w.w;
                    }
                }
            }
        }
        #pragma unroll
        for (int i = 0; i < 8; ++i) {
            int n = n0 + ng + 16 * i;
            if (n < N) *(float4*)&h[(size_t)n * 128 + jh * 64 + cg * 4] = acc[i];
        }
    }
}

// ---------------- layer 2 GEMM: y[N,128] @ W2[128,64] ----------------
// Full W2 (32KB) in LDS staged once; y read direct (streamed, L2/L3).

__global__ __launch_bounds__(256) void k_gemm2(
    const float* __restrict__ y, const float* __restrict__ W2,
    float* __restrict__ h2, int N)
{
    __shared__ float Wl[128][64];           // 32KB
    int t = threadIdx.x;
    for (int idx = t; idx < 128 * 64; idx += 256)
        Wl[idx >> 6][idx & 63] = W2[idx];
    __syncthreads();

    int cg = t & 15;
    int ng = t >> 4;
    int ntiles = (N + 127) >> 7;
    for (int tile = blockIdx.x; tile < ntiles; tile += gridDim.x) {
        int n0 = tile << 7;
        const float* rp[8];
        float4 acc[8];
        #pragma unroll
        for (int i = 0; i < 8; ++i) {
            acc[i] = make_float4(0.f, 0.f, 0.f, 0.f);
            int n = n0 + ng + 16 * i;
            rp[i] = y + (size_t)((n < N) ? n : (N - 1)) * 128;
        }
        #pragma unroll 4
        for (int k4 = 0; k4 < 32; ++k4) {
            float4 xv[8];
            #pragma unroll
            for (int i = 0; i < 8; ++i)
                xv[i] = *(const float4*)(rp[i] + k4 * 4);
            #pragma unroll
            for (int kk = 0; kk < 4; ++kk) {
                float4 w = *(const float4*)&Wl[k4 * 4 + kk][cg * 4];
                #pragma unroll
                for (int i = 0; i < 8; ++i) {
                    float xx = (kk == 0) ? xv[i].x : (kk == 1) ? xv[i].y
                             : (kk == 2) ? xv[i].z : xv[i].w;
                    acc[i].x += xx * w.x;
                    acc[i].y += xx * w.y;
                    acc[i].z += xx * w.z;
                    acc[i].w += xx * w.w;
                }
            }
        }
        #pragma unroll
        for (int i = 0; i < 8; ++i) {
            int n = n0 + ng + 16 * i;
            if (n < N) *(float4*)&h2[(size_t)n * 64 + cg * 4] = acc[i];
        }
    }
}

// ---------------- layer 1 aggregation: 1 wave per dst node, float2/lane ----------------

__global__ __launch_bounds__(256) void k_agg1(
    const float* __restrict__ h, const int* __restrict__ rowp, const int* __restrict__ col,
    const float* __restrict__ dinv, const float* __restrict__ b1,
    float* __restrict__ y, int N)
{
    int wv = threadIdx.x >> 6;
    int lane = threadIdx.x & 63;
    int d = blockIdx.x * 4 + wv;
    if (d >= N) return;
    float dd = dinv[d];
    float2 self = *(const float2*)&h[(size_t)d * 128 + lane * 2];
    float a0x = self.x * dd * dd, a0y = self.y * dd * dd;
    float a1x = 0.f, a1y = 0.f, a2x = 0.f, a2y = 0.f, a3x = 0.f, a3y = 0.f;
    int e = rowp[d], e1 = rowp[d + 1];
    for (; e + 4 <= e1; e += 4) {
        int s0 = col[e], s1 = col[e + 1], s2 = col[e + 2], s3 = col[e + 3];
        float w0 = dinv[s0] * dd, w1 = dinv[s1] * dd;
        float w2 = dinv[s2] * dd, w3 = dinv[s3] * dd;
        float2 v0 = *(const float2*)&h[(size_t)s0 * 128 + lane * 2];
        float2 v1 = *(const float2*)&h[(size_t)s1 * 128 + lane * 2];
        float2 v2 = *(const float2*)&h[(size_t)s2 * 128 + lane * 2];
        float2 v3 = *(const float2*)&h[(size_t)s3 * 128 + lane * 2];
        a0x += v0.x * w0; a0y += v0.y * w0;
        a1x += v1.x * w1; a1y += v1.y * w1;
        a2x += v2.x * w2; a2y += v2.y * w2;
        a3x += v3.x * w3; a3y += v3.y * w3;
    }
    for (; e < e1; ++e) {
        int s = col[e];
        float w = dinv[s] * dd;
        float2 v = *(const float2*)&h[(size_t)s * 128 + lane * 2];
        a0x += v.x * w; a0y += v.y * w;
    }
    float2 bb = *(const float2*)&b1[lane * 2];
    float rx = a0x + a1x + a2x + a3x + bb.x;
    float ry = a0y + a1y + a2y + a3y + bb.y;
    float2 r;
    r.x = rx > 0.f ? rx : 0.f;
    r.y = ry > 0.f ? ry : 0.f;
    *(float2*)&y[(size_t)d * 128 + lane * 2] = r;
}

// ---------------- layer 2 aggregation: 1 wave per dst node, 1 float/lane ----------------

__global__ __launch_bounds__(256) void k_agg2(
    const float* __restrict__ h2, const int* __restrict__ rowp, const int* __restrict__ col,
    const float* __restrict__ dinv, const float* __restrict__ b2,
    float* __restrict__ out, int N)
{
    int wv = threadIdx.x >> 6;
    int lane = threadIdx.x & 63;
    int d = blockIdx.x * 4 + wv;
    if (d >= N) return;
    float dd = dinv[d];
    float a0 = h2[(size_t)d * 64 + lane] * dd * dd;
    float a1 = 0.f, a2 = 0.f, a3 = 0.f;
    int e = rowp[d], e1 = rowp[d + 1];
    for (; e + 4 <= e1; e += 4) {
        int s0 = col[e], s1 = col[e + 1], s2 = col[e + 2], s3 = col[e + 3];
        float w0 = dinv[s0] * dd, w1 = dinv[s1] * dd;
        float w2 = dinv[s2] * dd, w3 = dinv[s3] * dd;
        a0 += h2[(size_t)s0 * 64 + lane] * w0;
        a1 += h2[(size_t)s1 * 64 + lane] * w1;
        a2 += h2[(size_t)s2 * 64 + lane] * w2;
        a3 += h2[(size_t)s3 * 64 + lane] * w3;
    }
    for (; e < e1; ++e) {
        int s = col[e];
        a0 += h2[(size_t)s * 64 + lane] * (dinv[s] * dd);
    }
    float v = a0 + a1 + a2 + a3 + b2[lane];
    out[(size_t)d * 64 + lane] = v > 0.f ? v : 0.f;
}

// ---------------- launch ----------------

extern "C" void kernel_launch(void* const* d_in, const int* in_sizes, int n_in,
                              void* d_out, int out_size, void* d_ws, size_t ws_size,
                              hipStream_t stream) {
    const int*   cid    = (const int*)d_in[0];
    const int*   sid    = (const int*)d_in[1];
    const int*   eid    = (const int*)d_in[2];
    const int*   edge   = (const int*)d_in[3];
    const float* cat_t  = (const float*)d_in[4];
    const float* sub_t  = (const float*)d_in[5];
    const float* elem_t = (const float*)d_in[6];
    const float* W1     = (const float*)d_in[7];
    const float* b1     = (const float*)d_in[8];
    const float* W2     = (const float*)d_in[9];
    const float* b2     = (const float*)d_in[10];
    float* out = (float*)d_out;

    int N = in_sizes[0];
    int E = in_sizes[3] / 2;
    const int* src = edge;
    const int* dst = edge + E;

    int*   ws   = (int*)d_ws;
    int*   deg  = ws + OFF_DEG;
    float* dinv = (float*)(ws + OFF_DINV);
    int*   rowp = ws + OFF_ROWP;
    int*   fill = ws + OFF_FILL;
    int*   col  = ws + OFF_COL;
    float* h    = (float*)(ws + OFF_H);
    float* y    = (float*)(ws + OFF_Y);
    int*   bsum = ws + OFF_BSUM;

    hipMemsetAsync(deg, 0, (size_t)N * sizeof(int), stream);

    k_deg<<<2048, 256, 0, stream>>>(dst, E, deg);
    k_dinv<<<(N + 255) / 256, 256, 0, stream>>>(deg, dinv, N);

    int nb = (N + 1023) / 1024;
    k_scan1<<<nb, 256, 0, stream>>>(deg, N, rowp, bsum);
    k_scan2<<<1, 256, 0, stream>>>(bsum, nb);
    k_scan3<<<nb, 256, 0, stream>>>(rowp, bsum, N, E, fill);
    k_scatter<<<2048, 256, 0, stream>>>(src, dst, E, fill, col);

    k_gemm1<<<768, 256, 0, stream>>>(cid, sid, eid, cat_t, sub_t, elem_t, W1, h, N);
    k_agg1<<<(N + 3) / 4, 256, 0, stream>>>(h, rowp, col, dinv, b1, y, N);
    k_gemm2<<<782, 256, 0, stream>>>(y, W2, h, N);       // h reused as h2
    k_agg2<<<(N + 3) / 4, 256, 0, stream>>>(h, rowp, col, dinv, b2, out, N);
}

// Round 4
// 625.134 us; speedup vs baseline: 1.5721x; 1.0830x over previous
//
#include <hip/hip_runtime.h>

#define N_NODES 100000
#define EMB     64
#define H1      128
#define H2      64

// workspace layout (in 4-byte elements)
#define OFF_DEG   0
#define OFF_DINV  100000
#define OFF_ROWP  200000      // N+1 entries, padded
#define OFF_FILL  300004
#define OFF_COL   400004
#define OFF_H     2000004     // h region: N*128 ushort (layer1) / N*64 ushort (layer2)
#define OFF_Y     14800004    // N*128 floats (layer1 post-relu)
#define OFF_BSUM  27600004    // scan block sums

static __device__ __forceinline__ unsigned short f2bf(float f) {
    unsigned int u = __float_as_uint(f);
    unsigned int r = (u + 0x7fffu + ((u >> 16) & 1u)) >> 16;   // RNE
    return (unsigned short)r;
}
static __device__ __forceinline__ unsigned int pack2bf(float a, float b) {
    return (unsigned int)f2bf(a) | ((unsigned int)f2bf(b) << 16);
}
static __device__ __forceinline__ float bflo(unsigned int u) {
    return __uint_as_float(u << 16);
}
static __device__ __forceinline__ float bfhi(unsigned int u) {
    return __uint_as_float(u & 0xffff0000u);
}

// ---------------- degree / dinv ----------------

__global__ void k_deg(const int* __restrict__ dst, int E, int* __restrict__ deg) {
    int i = blockIdx.x * blockDim.x + threadIdx.x;
    int stride = gridDim.x * blockDim.x;
    for (; i < E; i += stride) atomicAdd(&deg[dst[i]], 1);
}

__global__ void k_dinv(const int* __restrict__ deg, float* __restrict__ dinv, int N) {
    int i = blockIdx.x * blockDim.x + threadIdx.x;
    if (i < N) dinv[i] = rsqrtf((float)(deg[i] + 1));   // +1 self-loop
}

// ---------------- exclusive scan (3-kernel) ----------------

__global__ void k_scan1(const int* __restrict__ deg, int N,
                        int* __restrict__ rowp, int* __restrict__ bsum) {
    __shared__ int sh[256];
    int b = blockIdx.x, t = threadIdx.x;
    int base = b * 1024 + t * 4;
    int v0 = (base + 0 < N) ? deg[base + 0] : 0;
    int v1 = (base + 1 < N) ? deg[base + 1] : 0;
    int v2 = (base + 2 < N) ? deg[base + 2] : 0;
    int v3 = (base + 3 < N) ? deg[base + 3] : 0;
    sh[t] = v0 + v1 + v2 + v3;
    __syncthreads();
    for (int off = 1; off < 256; off <<= 1) {
        int x = (t >= off) ? sh[t - off] : 0;
        __syncthreads();
        sh[t] += x;
        __syncthreads();
    }
    if (t == 255) bsum[b] = sh[255];
    int run = (t == 0) ? 0 : sh[t - 1];
    if (base + 0 < N) rowp[base + 0] = run; run += v0;
    if (base + 1 < N) rowp[base + 1] = run; run += v1;
    if (base + 2 < N) rowp[base + 2] = run; run += v2;
    if (base + 3 < N) rowp[base + 3] = run;
}

__global__ void k_scan2(int* __restrict__ bsum, int nb) {
    __shared__ int sh[256];
    int t = threadIdx.x;
    sh[t] = (t < nb) ? bsum[t] : 0;
    __syncthreads();
    for (int off = 1; off < 256; off <<= 1) {
        int x = (t >= off) ? sh[t - off] : 0;
        __syncthreads();
        sh[t] += x;
        __syncthreads();
    }
    int excl = (t == 0) ? 0 : sh[t - 1];
    if (t < nb) bsum[t] = excl;
}

__global__ void k_scan3(int* __restrict__ rowp, const int* __restrict__ bsum,
                        int N, int E, int* __restrict__ fill) {
    int b = blockIdx.x, t = threadIdx.x;
    int base = b * 1024 + t * 4;
    int add = bsum[b];
    #pragma unroll
    for (int u = 0; u < 4; ++u) {
        int i = base + u;
        if (i < N) { int r = rowp[i] + add; rowp[i] = r; fill[i] = r; }
    }
    if (b == 0 && t == 0) rowp[N] = E;
}

__global__ void k_scatter(const int* __restrict__ src, const int* __restrict__ dst, int E,
                          int* __restrict__ fill, int* __restrict__ col) {
    int i = blockIdx.x * blockDim.x + threadIdx.x;
    int stride = gridDim.x * blockDim.x;
    for (; i < E; i += stride) {
        int d = dst[i];
        int pos = atomicAdd(&fill[d], 1);
        col[pos] = src[i];
    }
}

// ---------------- layer 1 GEMM: x(emb concat)[N,192] @ W1[192,128] ----------------
// Epilogue: scale by dinv[n], pack bf16 -> hb (h' = dinv*h).

__global__ __launch_bounds__(256) void k_gemm1(
    const int* __restrict__ cid, const int* __restrict__ sid, const int* __restrict__ eid,
    const float* __restrict__ cat_t, const float* __restrict__ sub_t,
    const float* __restrict__ elem_t, const float* __restrict__ W1,
    const float* __restrict__ dinv,
    unsigned short* __restrict__ hb, int N)
{
    __shared__ float Wl[192][64];           // 48KB -> 3 blocks/CU
    int t = threadIdx.x;
    int jh = blockIdx.x & 1;
    for (int idx = t; idx < 192 * 64; idx += 256) {
        int k = idx >> 6, j = idx & 63;
        Wl[k][j] = W1[k * 128 + jh * 64 + j];
    }
    __syncthreads();

    int cg = t & 15;          // 4 cols: cg*4..+3 (within the 64-col half)
    int ng = t >> 4;          // 8 nodes: n0 + ng + 16*i
    int ntiles = (N + 127) >> 7;
    int tstride = gridDim.x >> 1;
    for (int tile = blockIdx.x >> 1; tile < ntiles; tile += tstride) {
        int n0 = tile << 7;
        float4 acc[8];
        #pragma unroll
        for (int i = 0; i < 8; ++i) acc[i] = make_float4(0.f, 0.f, 0.f, 0.f);

        #pragma unroll
        for (int seg = 0; seg < 3; ++seg) {
            const float* tab = (seg == 0) ? cat_t : (seg == 1) ? sub_t : elem_t;
            const int*   ids = (seg == 0) ? cid   : (seg == 1) ? sid   : eid;
            const float* rp[8];
            #pragma unroll
            for (int i = 0; i < 8; ++i) {
                int n = n0 + ng + 16 * i;
                int id = ids[(n < N) ? n : 0];
                rp[i] = tab + (size_t)id * 64;
            }
            #pragma unroll 4
            for (int k4 = 0; k4 < 16; ++k4) {
                float4 xv[8];
                #pragma unroll
                for (int i = 0; i < 8; ++i)
                    xv[i] = *(const float4*)(rp[i] + k4 * 4);
                #pragma unroll
                for (int kk = 0; kk < 4; ++kk) {
                    float4 w = *(const float4*)&Wl[seg * 64 + k4 * 4 + kk][cg * 4];
                    #pragma unroll
                    for (int i = 0; i < 8; ++i) {
                        float xx = (kk == 0) ? xv[i].x : (kk == 1) ? xv[i].y
                                 : (kk == 2) ? xv[i].z : xv[i].w;
                        acc[i].x += xx * w.x;
                        acc[i].y += xx * w.y;
                        acc[i].z += xx * w.z;
                        acc[i].w += xx * w.w;
                    }
                }
            }
        }
        #pragma unroll
        for (int i = 0; i < 8; ++i) {
            int n = n0 + ng + 16 * i;
            if (n < N) {
                float s = dinv[n];
                uint2 p;
                p.x = pack2bf(acc[i].x * s, acc[i].y * s);
                p.y = pack2bf(acc[i].z * s, acc[i].w * s);
                *(uint2*)(hb + (size_t)n * 128 + jh * 64 + cg * 4) = p;
            }
        }
    }
}

// ---------------- layer 2 GEMM: y[N,128] @ W2[128,64] ----------------
// Epilogue: scale by dinv[n], pack bf16 -> h2b.

__global__ __launch_bounds__(256) void k_gemm2(
    const float* __restrict__ y, const float* __restrict__ W2,
    const float* __restrict__ dinv,
    unsigned short* __restrict__ h2b, int N)
{
    __shared__ float Wl[128][64];           // 32KB
    int t = threadIdx.x;
    for (int idx = t; idx < 128 * 64; idx += 256)
        Wl[idx >> 6][idx & 63] = W2[idx];
    __syncthreads();

    int cg = t & 15;
    int ng = t >> 4;
    int ntiles = (N + 127) >> 7;
    for (int tile = blockIdx.x; tile < ntiles; tile += gridDim.x) {
        int n0 = tile << 7;
        const float* rp[8];
        float4 acc[8];
        #pragma unroll
        for (int i = 0; i < 8; ++i) {
            acc[i] = make_float4(0.f, 0.f, 0.f, 0.f);
            int n = n0 + ng + 16 * i;
            rp[i] = y + (size_t)((n < N) ? n : (N - 1)) * 128;
        }
        #pragma unroll 4
        for (int k4 = 0; k4 < 32; ++k4) {
            float4 xv[8];
            #pragma unroll
            for (int i = 0; i < 8; ++i)
                xv[i] = *(const float4*)(rp[i] + k4 * 4);
            #pragma unroll
            for (int kk = 0; kk < 4; ++kk) {
                float4 w = *(const float4*)&Wl[k4 * 4 + kk][cg * 4];
                #pragma unroll
                for (int i = 0; i < 8; ++i) {
                    float xx = (kk == 0) ? xv[i].x : (kk == 1) ? xv[i].y
                             : (kk == 2) ? xv[i].z : xv[i].w;
                    acc[i].x += xx * w.x;
                    acc[i].y += xx * w.y;
                    acc[i].z += xx * w.z;
                    acc[i].w += xx * w.w;
                }
            }
        }
        #pragma unroll
        for (int i = 0; i < 8; ++i) {
            int n = n0 + ng + 16 * i;
            if (n < N) {
                float s = dinv[n];
                uint2 p;
                p.x = pack2bf(acc[i].x * s, acc[i].y * s);
                p.y = pack2bf(acc[i].z * s, acc[i].w * s);
                *(uint2*)(h2b + (size_t)n * 64 + cg * 4) = p;
            }
        }
    }
}

// ---------------- layer 1 aggregation: 1 wave per dst node, 2 bf16 cols/lane ----------------
// hb rows are pre-scaled by dinv[src]; y[d] = relu(dd * (self' + sum of neighbor rows) + b1)

__global__ __launch_bounds__(256) void k_agg1(
    const unsigned short* __restrict__ hb, const int* __restrict__ rowp,
    const int* __restrict__ col, const float* __restrict__ dinv,
    const float* __restrict__ b1, float* __restrict__ y, int N)
{
    int wv = threadIdx.x >> 6;
    int lane = threadIdx.x & 63;
    int d = blockIdx.x * 4 + wv;
    if (d >= N) return;
    const unsigned int* hp = (const unsigned int*)hb;   // 64 uints per row
    float dd = dinv[d];
    unsigned int su = hp[(size_t)d * 64 + lane];
    float ax0 = bflo(su), ay0 = bfhi(su);               // self' = dd*h[d]
    float ax1 = 0.f, ay1 = 0.f, ax2 = 0.f, ay2 = 0.f, ax3 = 0.f, ay3 = 0.f;
    float ax4 = 0.f, ay4 = 0.f, ax5 = 0.f, ay5 = 0.f, ax6 = 0.f, ay6 = 0.f;
    float ax7 = 0.f, ay7 = 0.f;
    int e = rowp[d], e1 = rowp[d + 1];
    for (; e + 8 <= e1; e += 8) {
        int s0 = col[e + 0], s1 = col[e + 1], s2 = col[e + 2], s3 = col[e + 3];
        int s4 = col[e + 4], s5 = col[e + 5], s6 = col[e + 6], s7 = col[e + 7];
        unsigned int u0 = hp[(size_t)s0 * 64 + lane];
        unsigned int u1 = hp[(size_t)s1 * 64 + lane];
        unsigned int u2 = hp[(size_t)s2 * 64 + lane];
        unsigned int u3 = hp[(size_t)s3 * 64 + lane];
        unsigned int u4 = hp[(size_t)s4 * 64 + lane];
        unsigned int u5 = hp[(size_t)s5 * 64 + lane];
        unsigned int u6 = hp[(size_t)s6 * 64 + lane];
        unsigned int u7 = hp[(size_t)s7 * 64 + lane];
        ax0 += bflo(u0); ay0 += bfhi(u0);
        ax1 += bflo(u1); ay1 += bfhi(u1);
        ax2 += bflo(u2); ay2 += bfhi(u2);
        ax3 += bflo(u3); ay3 += bfhi(u3);
        ax4 += bflo(u4); ay4 += bfhi(u4);
        ax5 += bflo(u5); ay5 += bfhi(u5);
        ax6 += bflo(u6); ay6 += bfhi(u6);
        ax7 += bflo(u7); ay7 += bfhi(u7);
    }
    for (; e < e1; ++e) {
        unsigned int u = hp[(size_t)col[e] * 64 + lane];
        ax0 += bflo(u); ay0 += bfhi(u);
    }
    float2 bb = *(const float2*)&b1[lane * 2];
    float rx = dd * (((ax0 + ax1) + (ax2 + ax3)) + ((ax4 + ax5) + (ax6 + ax7))) + bb.x;
    float ry = dd * (((ay0 + ay1) + (ay2 + ay3)) + ((ay4 + ay5) + (ay6 + ay7))) + bb.y;
    float2 r;
    r.x = rx > 0.f ? rx : 0.f;
    r.y = ry > 0.f ? ry : 0.f;
    *(float2*)&y[(size_t)d * 128 + lane * 2] = r;
}

// ---------------- layer 2 aggregation: 1 wave per dst node, 1 bf16 col/lane ----------------

__global__ __launch_bounds__(256) void k_agg2(
    const unsigned short* __restrict__ h2b, const int* __restrict__ rowp,
    const int* __restrict__ col, const float* __restrict__ dinv,
    const float* __restrict__ b2, float* __restrict__ out, int N)
{
    int wv = threadIdx.x >> 6;
    int lane = threadIdx.x & 63;
    int d = blockIdx.x * 4 + wv;
    if (d >= N) return;
    float dd = dinv[d];
    float a0 = __uint_as_float((unsigned int)h2b[(size_t)d * 64 + lane] << 16);
    float a1 = 0.f, a2 = 0.f, a3 = 0.f, a4 = 0.f, a5 = 0.f, a6 = 0.f, a7 = 0.f;
    int e = rowp[d], e1 = rowp[d + 1];
    for (; e + 8 <= e1; e += 8) {
        int s0 = col[e + 0], s1 = col[e + 1], s2 = col[e + 2], s3 = col[e + 3];
        int s4 = col[e + 4], s5 = col[e + 5], s6 = col[e + 6], s7 = col[e + 7];
        a0 += __uint_as_float((unsigned int)h2b[(size_t)s0 * 64 + lane] << 16);
        a1 += __uint_as_float((unsigned int)h2b[(size_t)s1 * 64 + lane] << 16);
        a2 += __uint_as_float((unsigned int)h2b[(size_t)s2 * 64 + lane] << 16);
        a3 += __uint_as_float((unsigned int)h2b[(size_t)s3 * 64 + lane] << 16);
        a4 += __uint_as_float((unsigned int)h2b[(size_t)s4 * 64 + lane] << 16);
        a5 += __uint_as_float((unsigned int)h2b[(size_t)s5 * 64 + lane] << 16);
        a6 += __uint_as_float((unsigned int)h2b[(size_t)s6 * 64 + lane] << 16);
        a7 += __uint_as_float((unsigned int)h2b[(size_t)s7 * 64 + lane] << 16);
    }
    for (; e < e1; ++e)
        a0 += __uint_as_float((unsigned int)h2b[(size_t)col[e] * 64 + lane] << 16);
    float v = dd * (((a0 + a1) + (a2 + a3)) + ((a4 + a5) + (a6 + a7))) + b2[lane];
    out[(size_t)d * 64 + lane] = v > 0.f ? v : 0.f;
}

// ---------------- launch ----------------

extern "C" void kernel_launch(void* const* d_in, const int* in_sizes, int n_in,
                              void* d_out, int out_size, void* d_ws, size_t ws_size,
                              hipStream_t stream) {
    const int*   cid    = (const int*)d_in[0];
    const int*   sid    = (const int*)d_in[1];
    const int*   eid    = (const int*)d_in[2];
    const int*   edge   = (const int*)d_in[3];
    const float* cat_t  = (const float*)d_in[4];
    const float* sub_t  = (const float*)d_in[5];
    const float* elem_t = (const float*)d_in[6];
    const float* W1     = (const float*)d_in[7];
    const float* b1     = (const float*)d_in[8];
    const float* W2     = (const float*)d_in[9];
    const float* b2     = (const float*)d_in[10];
    float* out = (float*)d_out;

    int N = in_sizes[0];
    int E = in_sizes[3] / 2;
    const int* src = edge;
    const int* dst = edge + E;

    int*   ws   = (int*)d_ws;
    int*   deg  = ws + OFF_DEG;
    float* dinv = (float*)(ws + OFF_DINV);
    int*   rowp = ws + OFF_ROWP;
    int*   fill = ws + OFF_FILL;
    int*   col  = ws + OFF_COL;
    unsigned short* hb = (unsigned short*)(ws + OFF_H);   // bf16 h / h2
    float* y    = (float*)(ws + OFF_Y);
    int*   bsum = ws + OFF_BSUM;

    hipMemsetAsync(deg, 0, (size_t)N * sizeof(int), stream);

    k_deg<<<2048, 256, 0, stream>>>(dst, E, deg);
    k_dinv<<<(N + 255) / 256, 256, 0, stream>>>(deg, dinv, N);

    int nb = (N + 1023) / 1024;
    k_scan1<<<nb, 256, 0, stream>>>(deg, N, rowp, bsum);
    k_scan2<<<1, 256, 0, stream>>>(bsum, nb);
    k_scan3<<<nb, 256, 0, stream>>>(rowp, bsum, N, E, fill);
    k_scatter<<<2048, 256, 0, stream>>>(src, dst, E, fill, col);

    k_gemm1<<<768, 256, 0, stream>>>(cid, sid, eid, cat_t, sub_t, elem_t, W1, dinv, hb, N);
    k_agg1<<<(N + 3) / 4, 256, 0, stream>>>(hb, rowp, col, dinv, b1, y, N);
    k_gemm2<<<782, 256, 0, stream>>>(y, W2, dinv, hb, N);   // hb reused as h2 bf16
    k_agg2<<<(N + 3) / 4, 256, 0, stream>>>(hb, rowp, col, dinv, b2, out, N);
}

// Round 5
// 573.236 us; speedup vs baseline: 1.7144x; 1.0905x over previous
//
#include <hip/hip_runtime.h>

#define N_NODES 100000
#define EMB     64
#define H1      128
#define H2      64

// workspace layout (in 4-byte elements) — stays under the proven ~110.4MB envelope
#define OFF_DEG   0
#define OFF_DINV  100000
#define OFF_ROWP  200000      // N+1 entries
#define OFF_FILL  300004
#define OFF_COL   400004      // E ints -> ends 2000004
#define OFF_H     2000004     // h: N*128 ushort (6.4M ints); reused as h2 (N*64 ushort)
#define OFF_Y     14800004    // y: N*128 ushort (6.4M ints) -> ends 21200004
#define OFF_PCAT  21300000    // 1000*128 floats
#define OFF_PSUB  21500000    // 5000*128 floats -> ends 22140000
#define OFF_BSUM  27600004    // scan block sums

static __device__ __forceinline__ unsigned short f2bf(float f) {
    unsigned int u = __float_as_uint(f);
    unsigned int r = (u + 0x7fffu + ((u >> 16) & 1u)) >> 16;   // RNE
    return (unsigned short)r;
}
static __device__ __forceinline__ unsigned int pack2bf(float a, float b) {
    return (unsigned int)f2bf(a) | ((unsigned int)f2bf(b) << 16);
}
static __device__ __forceinline__ float bflo(unsigned int u) {
    return __uint_as_float(u << 16);
}
static __device__ __forceinline__ float bfhi(unsigned int u) {
    return __uint_as_float(u & 0xffff0000u);
}

// ---------------- degree / dinv ----------------

__global__ void k_deg(const int* __restrict__ dst, int E, int* __restrict__ deg) {
    int i = blockIdx.x * blockDim.x + threadIdx.x;
    int stride = gridDim.x * blockDim.x;
    for (; i < E; i += stride) atomicAdd(&deg[dst[i]], 1);
}

__global__ void k_dinv(const int* __restrict__ deg, float* __restrict__ dinv, int N) {
    int i = blockIdx.x * blockDim.x + threadIdx.x;
    if (i < N) dinv[i] = rsqrtf((float)(deg[i] + 1));   // +1 self-loop
}

// ---------------- exclusive scan (3-kernel) ----------------

__global__ void k_scan1(const int* __restrict__ deg, int N,
                        int* __restrict__ rowp, int* __restrict__ bsum) {
    __shared__ int sh[256];
    int b = blockIdx.x, t = threadIdx.x;
    int base = b * 1024 + t * 4;
    int v0 = (base + 0 < N) ? deg[base + 0] : 0;
    int v1 = (base + 1 < N) ? deg[base + 1] : 0;
    int v2 = (base + 2 < N) ? deg[base + 2] : 0;
    int v3 = (base + 3 < N) ? deg[base + 3] : 0;
    sh[t] = v0 + v1 + v2 + v3;
    __syncthreads();
    for (int off = 1; off < 256; off <<= 1) {
        int x = (t >= off) ? sh[t - off] : 0;
        __syncthreads();
        sh[t] += x;
        __syncthreads();
    }
    if (t == 255) bsum[b] = sh[255];
    int run = (t == 0) ? 0 : sh[t - 1];
    if (base + 0 < N) rowp[base + 0] = run; run += v0;
    if (base + 1 < N) rowp[base + 1] = run; run += v1;
    if (base + 2 < N) rowp[base + 2] = run; run += v2;
    if (base + 3 < N) rowp[base + 3] = run;
}

__global__ void k_scan2(int* __restrict__ bsum, int nb) {
    __shared__ int sh[256];
    int t = threadIdx.x;
    sh[t] = (t < nb) ? bsum[t] : 0;
    __syncthreads();
    for (int off = 1; off < 256; off <<= 1) {
        int x = (t >= off) ? sh[t - off] : 0;
        __syncthreads();
        sh[t] += x;
        __syncthreads();
    }
    int excl = (t == 0) ? 0 : sh[t - 1];
    if (t < nb) bsum[t] = excl;
}

__global__ void k_scan3(int* __restrict__ rowp, const int* __restrict__ bsum,
                        int N, int E, int* __restrict__ fill) {
    int b = blockIdx.x, t = threadIdx.x;
    int base = b * 1024 + t * 4;
    int add = bsum[b];
    #pragma unroll
    for (int u = 0; u < 4; ++u) {
        int i = base + u;
        if (i < N) { int r = rowp[i] + add; rowp[i] = r; fill[i] = r; }
    }
    if (b == 0 && t == 0) rowp[N] = E;
}

__global__ void k_scatter(const int* __restrict__ src, const int* __restrict__ dst, int E,
                          int* __restrict__ fill, int* __restrict__ col) {
    int i = blockIdx.x * blockDim.x + threadIdx.x;
    int stride = gridDim.x * blockDim.x;
    for (; i < E; i += stride) {
        int d = dst[i];
        int pos = atomicAdd(&fill[d], 1);
        col[pos] = src[i];
    }
}

// ---------------- small-table precompute: P = tab[R,64] @ Wseg[64,128] ----------------

__global__ __launch_bounds__(256) void k_ptab(
    const float* __restrict__ tab, const float* __restrict__ Wseg,
    float* __restrict__ P, int R)
{
    __shared__ float Wl[64][128];          // 32KB
    int t = threadIdx.x;
    for (int idx = t; idx < 64 * 128; idx += 256)
        Wl[idx >> 7][idx & 127] = Wseg[idx];
    __syncthreads();
    int cg = t & 31, ng = t >> 5;          // 8 rows/block, 4 cols/thread
    int r = blockIdx.x * 8 + ng;
    if (r >= R) return;
    const float* x = tab + (size_t)r * 64;
    float4 acc = make_float4(0.f, 0.f, 0.f, 0.f);
    #pragma unroll 8
    for (int k = 0; k < 64; ++k) {
        float xx = x[k];
        float4 w = *(const float4*)&Wl[k][cg * 4];
        acc.x += xx * w.x; acc.y += xx * w.y;
        acc.z += xx * w.z; acc.w += xx * w.w;
    }
    *(float4*)&P[(size_t)r * 128 + cg * 4] = acc;
}

// ---------------- layer 1 GEMM: h[n] = elem_emb[eid[n]]@W1c + Pcat[cid] + Psub[sid] ----
// W1c (rows 128..191 of W1) full-width in 32KB LDS. 64-node tile, thread = 8 nodes x 4 cols.
// Epilogue: + P gathers, scale by dinv[n], pack bf16.

__global__ __launch_bounds__(256) void k_gemm1(
    const int* __restrict__ cid, const int* __restrict__ sid, const int* __restrict__ eid,
    const float* __restrict__ elem_t, const float* __restrict__ W1,
    const float* __restrict__ Pcat, const float* __restrict__ Psub,
    const float* __restrict__ dinv,
    unsigned short* __restrict__ hb, int N)
{
    __shared__ float Wl[64][128];          // 32KB
    int t = threadIdx.x;
    const float* Wc = W1 + 128 * 128;      // rows 128..191
    for (int idx = t; idx < 64 * 128; idx += 256)
        Wl[idx >> 7][idx & 127] = Wc[idx];
    __syncthreads();

    int cg = t & 31;                       // 4 cols: cg*4..+3 of 128
    int ng = t >> 5;                       // 8 node-groups
    int n0 = blockIdx.x << 6;              // 64-node tile

    const float* rp[8];
    #pragma unroll
    for (int i = 0; i < 8; ++i) {
        int n = n0 + ng + 8 * i;
        int id = eid[(n < N) ? n : 0];
        rp[i] = elem_t + (size_t)id * 64;
    }
    float4 acc[8];
    #pragma unroll
    for (int i = 0; i < 8; ++i) acc[i] = make_float4(0.f, 0.f, 0.f, 0.f);

    #pragma unroll 4
    for (int k4 = 0; k4 < 16; ++k4) {
        float4 xv[8];
        #pragma unroll
        for (int i = 0; i < 8; ++i)
            xv[i] = *(const float4*)(rp[i] + k4 * 4);
        #pragma unroll
        for (int kk = 0; kk < 4; ++kk) {
            float4 w = *(const float4*)&Wl[k4 * 4 + kk][cg * 4];
            #pragma unroll
            for (int i = 0; i < 8; ++i) {
                float xx = (kk == 0) ? xv[i].x : (kk == 1) ? xv[i].y
                         : (kk == 2) ? xv[i].z : xv[i].w;
                acc[i].x += xx * w.x;
                acc[i].y += xx * w.y;
                acc[i].z += xx * w.z;
                acc[i].w += xx * w.w;
            }
        }
    }
    #pragma unroll
    for (int i = 0; i < 8; ++i) {
        int n = n0 + ng + 8 * i;
        if (n < N) {
            float4 pc = *(const float4*)&Pcat[(size_t)cid[n] * 128 + cg * 4];
            float4 ps = *(const float4*)&Psub[(size_t)sid[n] * 128 + cg * 4];
            float s = dinv[n];
            float hx = (acc[i].x + pc.x + ps.x) * s;
            float hy = (acc[i].y + pc.y + ps.y) * s;
            float hz = (acc[i].z + pc.z + ps.z) * s;
            float hw = (acc[i].w + pc.w + ps.w) * s;
            uint2 p;
            p.x = pack2bf(hx, hy);
            p.y = pack2bf(hz, hw);
            *(uint2*)(hb + (size_t)n * 128 + cg * 4) = p;
        }
    }
}

// ---------------- layer 2 GEMM: y(bf16)[N,128] @ W2[128,64] ----------------

__global__ __launch_bounds__(256) void k_gemm2(
    const unsigned int* __restrict__ yb, const float* __restrict__ W2,
    const float* __restrict__ dinv,
    unsigned short* __restrict__ h2b, int N)
{
    __shared__ float Wl[128][64];          // 32KB
    int t = threadIdx.x;
    for (int idx = t; idx < 128 * 64; idx += 256)
        Wl[idx >> 6][idx & 63] = W2[idx];
    __syncthreads();

    int cg = t & 15;                       // 4 cols of 64
    int ng = t >> 4;                       // 16 node-groups, 8 nodes each
    int n0 = blockIdx.x << 7;              // 128-node tile
    const unsigned int* rp[8];
    float4 acc[8];
    #pragma unroll
    for (int i = 0; i < 8; ++i) {
        acc[i] = make_float4(0.f, 0.f, 0.f, 0.f);
        int n = n0 + ng + 16 * i;
        rp[i] = yb + (size_t)((n < N) ? n : (N - 1)) * 64;   // 64 uints = 128 bf16
    }
    #pragma unroll 4
    for (int k4 = 0; k4 < 32; ++k4) {
        uint2 xv[8];
        #pragma unroll
        for (int i = 0; i < 8; ++i)
            xv[i] = *(const uint2*)(rp[i] + k4 * 2);
        #pragma unroll
        for (int kk = 0; kk < 4; ++kk) {
            float4 w = *(const float4*)&Wl[k4 * 4 + kk][cg * 4];
            #pragma unroll
            for (int i = 0; i < 8; ++i) {
                float xx = (kk == 0) ? bflo(xv[i].x) : (kk == 1) ? bfhi(xv[i].x)
                         : (kk == 2) ? bflo(xv[i].y) : bfhi(xv[i].y);
                acc[i].x += xx * w.x;
                acc[i].y += xx * w.y;
                acc[i].z += xx * w.z;
                acc[i].w += xx * w.w;
            }
        }
    }
    #pragma unroll
    for (int i = 0; i < 8; ++i) {
        int n = n0 + ng + 16 * i;
        if (n < N) {
            float s = dinv[n];
            uint2 p;
            p.x = pack2bf(acc[i].x * s, acc[i].y * s);
            p.y = pack2bf(acc[i].z * s, acc[i].w * s);
            *(uint2*)(h2b + (size_t)n * 64 + cg * 4) = p;
        }
    }
}

// ---------------- layer 1 aggregation: 1 wave per dst node, 2 bf16 cols/lane ----------------
// hb rows pre-scaled by dinv[src]; y = relu(dd*(self'+sum) + b1), packed bf16.

__global__ __launch_bounds__(256) void k_agg1(
    const unsigned short* __restrict__ hb, const int* __restrict__ rowp,
    const int* __restrict__ col, const float* __restrict__ dinv,
    const float* __restrict__ b1, unsigned int* __restrict__ yb, int N)
{
    int wv = threadIdx.x >> 6;
    int lane = threadIdx.x & 63;
    int d = blockIdx.x * 4 + wv;
    if (d >= N) return;
    const unsigned int* hp = (const unsigned int*)hb;   // 64 uints per row
    float dd = dinv[d];
    unsigned int su = hp[(size_t)d * 64 + lane];
    float ax0 = bflo(su), ay0 = bfhi(su);
    float ax1 = 0.f, ay1 = 0.f, ax2 = 0.f, ay2 = 0.f, ax3 = 0.f, ay3 = 0.f;
    float ax4 = 0.f, ay4 = 0.f, ax5 = 0.f, ay5 = 0.f, ax6 = 0.f, ay6 = 0.f;
    float ax7 = 0.f, ay7 = 0.f;
    int e = rowp[d], e1 = rowp[d + 1];
    for (; e + 8 <= e1; e += 8) {
        int s0 = col[e + 0], s1 = col[e + 1], s2 = col[e + 2], s3 = col[e + 3];
        int s4 = col[e + 4], s5 = col[e + 5], s6 = col[e + 6], s7 = col[e + 7];
        unsigned int u0 = hp[(size_t)s0 * 64 + lane];
        unsigned int u1 = hp[(size_t)s1 * 64 + lane];
        unsigned int u2 = hp[(size_t)s2 * 64 + lane];
        unsigned int u3 = hp[(size_t)s3 * 64 + lane];
        unsigned int u4 = hp[(size_t)s4 * 64 + lane];
        unsigned int u5 = hp[(size_t)s5 * 64 + lane];
        unsigned int u6 = hp[(size_t)s6 * 64 + lane];
        unsigned int u7 = hp[(size_t)s7 * 64 + lane];
        ax0 += bflo(u0); ay0 += bfhi(u0);
        ax1 += bflo(u1); ay1 += bfhi(u1);
        ax2 += bflo(u2); ay2 += bfhi(u2);
        ax3 += bflo(u3); ay3 += bfhi(u3);
        ax4 += bflo(u4); ay4 += bfhi(u4);
        ax5 += bflo(u5); ay5 += bfhi(u5);
        ax6 += bflo(u6); ay6 += bfhi(u6);
        ax7 += bflo(u7); ay7 += bfhi(u7);
    }
    for (; e < e1; ++e) {
        unsigned int u = hp[(size_t)col[e] * 64 + lane];
        ax0 += bflo(u); ay0 += bfhi(u);
    }
    float2 bb = *(const float2*)&b1[lane * 2];
    float rx = dd * (((ax0 + ax1) + (ax2 + ax3)) + ((ax4 + ax5) + (ax6 + ax7))) + bb.x;
    float ry = dd * (((ay0 + ay1) + (ay2 + ay3)) + ((ay4 + ay5) + (ay6 + ay7))) + bb.y;
    yb[(size_t)d * 64 + lane] = pack2bf(rx > 0.f ? rx : 0.f, ry > 0.f ? ry : 0.f);
}

// ---------------- layer 2 aggregation: 1 wave per dst node, 1 bf16 col/lane ----------------

__global__ __launch_bounds__(256) void k_agg2(
    const unsigned short* __restrict__ h2b, const int* __restrict__ rowp,
    const int* __restrict__ col, const float* __restrict__ dinv,
    const float* __restrict__ b2, float* __restrict__ out, int N)
{
    int wv = threadIdx.x >> 6;
    int lane = threadIdx.x & 63;
    int d = blockIdx.x * 4 + wv;
    if (d >= N) return;
    float dd = dinv[d];
    float a0 = __uint_as_float((unsigned int)h2b[(size_t)d * 64 + lane] << 16);
    float a1 = 0.f, a2 = 0.f, a3 = 0.f, a4 = 0.f, a5 = 0.f, a6 = 0.f, a7 = 0.f;
    int e = rowp[d], e1 = rowp[d + 1];
    for (; e + 8 <= e1; e += 8) {
        int s0 = col[e + 0], s1 = col[e + 1], s2 = col[e + 2], s3 = col[e + 3];
        int s4 = col[e + 4], s5 = col[e + 5], s6 = col[e + 6], s7 = col[e + 7];
        a0 += __uint_as_float((unsigned int)h2b[(size_t)s0 * 64 + lane] << 16);
        a1 += __uint_as_float((unsigned int)h2b[(size_t)s1 * 64 + lane] << 16);
        a2 += __uint_as_float((unsigned int)h2b[(size_t)s2 * 64 + lane] << 16);
        a3 += __uint_as_float((unsigned int)h2b[(size_t)s3 * 64 + lane] << 16);
        a4 += __uint_as_float((unsigned int)h2b[(size_t)s4 * 64 + lane] << 16);
        a5 += __uint_as_float((unsigned int)h2b[(size_t)s5 * 64 + lane] << 16);
        a6 += __uint_as_float((unsigned int)h2b[(size_t)s6 * 64 + lane] << 16);
        a7 += __uint_as_float((unsigned int)h2b[(size_t)s7 * 64 + lane] << 16);
    }
    for (; e < e1; ++e)
        a0 += __uint_as_float((unsigned int)h2b[(size_t)col[e] * 64 + lane] << 16);
    float v = dd * (((a0 + a1) + (a2 + a3)) + ((a4 + a5) + (a6 + a7))) + b2[lane];
    out[(size_t)d * 64 + lane] = v > 0.f ? v : 0.f;
}

// ---------------- launch ----------------

extern "C" void kernel_launch(void* const* d_in, const int* in_sizes, int n_in,
                              void* d_out, int out_size, void* d_ws, size_t ws_size,
                              hipStream_t stream) {
    const int*   cid    = (const int*)d_in[0];
    const int*   sid    = (const int*)d_in[1];
    const int*   eid    = (const int*)d_in[2];
    const int*   edge   = (const int*)d_in[3];
    const float* cat_t  = (const float*)d_in[4];
    const float* sub_t  = (const float*)d_in[5];
    const float* elem_t = (const float*)d_in[6];
    const float* W1     = (const float*)d_in[7];
    const float* b1     = (const float*)d_in[8];
    const float* W2     = (const float*)d_in[9];
    const float* b2     = (const float*)d_in[10];
    float* out = (float*)d_out;

    int N = in_sizes[0];
    int E = in_sizes[3] / 2;
    const int* src = edge;
    const int* dst = edge + E;

    int*   ws   = (int*)d_ws;
    int*   deg  = ws + OFF_DEG;
    float* dinv = (float*)(ws + OFF_DINV);
    int*   rowp = ws + OFF_ROWP;
    int*   fill = ws + OFF_FILL;
    int*   col  = ws + OFF_COL;
    unsigned short* hb = (unsigned short*)(ws + OFF_H);   // bf16 h / h2
    unsigned int*   yb = (unsigned int*)(ws + OFF_Y);     // bf16 y (packed pairs)
    float* Pcat = (float*)(ws + OFF_PCAT);
    float* Psub = (float*)(ws + OFF_PSUB);
    int*   bsum = ws + OFF_BSUM;

    hipMemsetAsync(deg, 0, (size_t)N * sizeof(int), stream);

    // small-table premultiplies (independent of CSR build)
    k_ptab<<<125, 256, 0, stream>>>(cat_t, W1,             Pcat, 1000);
    k_ptab<<<625, 256, 0, stream>>>(sub_t, W1 + 64 * 128,  Psub, 5000);

    k_deg<<<2048, 256, 0, stream>>>(dst, E, deg);
    k_dinv<<<(N + 255) / 256, 256, 0, stream>>>(deg, dinv, N);

    int nb = (N + 1023) / 1024;
    k_scan1<<<nb, 256, 0, stream>>>(deg, N, rowp, bsum);
    k_scan2<<<1, 256, 0, stream>>>(bsum, nb);
    k_scan3<<<nb, 256, 0, stream>>>(rowp, bsum, N, E, fill);
    k_scatter<<<2048, 256, 0, stream>>>(src, dst, E, fill, col);

    k_gemm1<<<(N + 63) / 64, 256, 0, stream>>>(cid, sid, eid, elem_t, W1, Pcat, Psub, dinv, hb, N);
    k_agg1<<<(N + 3) / 4, 256, 0, stream>>>(hb, rowp, col, dinv, b1, yb, N);
    k_gemm2<<<(N + 127) / 128, 256, 0, stream>>>(yb, W2, dinv, hb, N);
    k_agg2<<<(N + 3) / 4, 256, 0, stream>>>(hb, rowp, col, dinv, b2, out, N);
}

// Round 6
// 429.016 us; speedup vs baseline: 2.2908x; 1.3362x over previous
//
#include <hip/hip_runtime.h>

#define N_NODES 100000
#define EMB     64
#define H1      128
#define H2      64

#define BSHIFT  7
#define NBUCK   782            // ceil(100000 / 128)
#define CAP     3072           // max edges per bucket (mean 2048, sigma 45)

// workspace layout (4-byte elements), all 16B-aligned
#define OFF_DINV  0            // 100000 floats
#define OFF_ROWP  100004       // 100001 ints
#define OFF_COL   200008       // E ints
#define OFF_GFILL 1800008      // NBUCK ints
#define OFF_GBASE 1800792      // NBUCK+1 ints
#define OFF_SCR   1801576      // NBUCK*CAP uints (9.6MB)
#define OFF_H     4203880      // N*128 ushort (bf16 h; reused as h2 N*64)
#define OFF_Y     10603880     // N*64 uint (bf16 y pairs)
#define OFF_PCAT  17003880     // 1000*128 floats
#define OFF_PSUB  17131880     // 5000*128 floats

static __device__ __forceinline__ unsigned short f2bf(float f) {
    unsigned int u = __float_as_uint(f);
    unsigned int r = (u + 0x7fffu + ((u >> 16) & 1u)) >> 16;   // RNE
    return (unsigned short)r;
}
static __device__ __forceinline__ unsigned int pack2bf(float a, float b) {
    return (unsigned int)f2bf(a) | ((unsigned int)f2bf(b) << 16);
}
static __device__ __forceinline__ float bflo(unsigned int u) {
    return __uint_as_float(u << 16);
}
static __device__ __forceinline__ float bfhi(unsigned int u) {
    return __uint_as_float(u & 0xffff0000u);
}

// ---------------- CSR build pass 1: coarse binning ----------------
// Per block: LDS histogram of its edge chunk over NBUCK buckets, ONE global
// atomic per (block,bucket) to reserve a run, then packed writes in runs.

__global__ __launch_bounds__(256) void k_bin(
    const int* __restrict__ src, const int* __restrict__ dst, int E,
    int* __restrict__ gfill, unsigned int* __restrict__ scr)
{
    __shared__ int hist[NBUCK];
    __shared__ int basec[NBUCK];
    int t = threadIdx.x;
    for (int i = t; i < NBUCK; i += 256) hist[i] = 0;
    __syncthreads();
    int chunk = (E + gridDim.x - 1) / gridDim.x;
    int e0 = blockIdx.x * chunk;
    int e1 = min(e0 + chunk, E);
    for (int i = e0 + t; i < e1; i += 256)
        atomicAdd(&hist[dst[i] >> BSHIFT], 1);
    __syncthreads();
    for (int b = t; b < NBUCK; b += 256) {
        int c = hist[b];
        basec[b] = (c > 0) ? atomicAdd(&gfill[b], c) : 0;
        hist[b] = 0;                       // reuse as block-local cursor
    }
    __syncthreads();
    for (int i = e0 + t; i < e1; i += 256) {
        int d = dst[i];
        int b = d >> BSHIFT;
        int slot = basec[b] + atomicAdd(&hist[b], 1);
        if (slot < CAP)
            scr[(size_t)b * CAP + slot] =
                ((unsigned int)(d & 127) << 17) | (unsigned int)src[i];
    }
}

// ---------------- CSR build pass 2: scan bucket totals ----------------

__global__ __launch_bounds__(256) void k_bscan(
    const int* __restrict__ gfill, int* __restrict__ gbase,
    int* __restrict__ rowp, int E)
{
    __shared__ int sh[256];
    int t = threadIdx.x;
    int v[4]; int s = 0;
    #pragma unroll
    for (int u = 0; u < 4; ++u) {
        int i = t * 4 + u;
        v[u] = (i < NBUCK) ? gfill[i] : 0;
        s += v[u];
    }
    sh[t] = s;
    __syncthreads();
    for (int off = 1; off < 256; off <<= 1) {
        int x = (t >= off) ? sh[t - off] : 0;
        __syncthreads();
        sh[t] += x;
        __syncthreads();
    }
    int run = (t == 0) ? 0 : sh[t - 1];
    #pragma unroll
    for (int u = 0; u < 4; ++u) {
        int i = t * 4 + u;
        if (i < NBUCK) gbase[i] = run;
        run += v[u];
    }
    if (t == 255) { gbase[NBUCK] = run; rowp[N_NODES] = E; }
}

// ---------------- CSR build pass 3: in-bucket counting sort ----------------
// One block per bucket (<=128 nodes). Emits col (coalesced within bucket range),
// rowp, and dinv directly — replaces deg/dinv/scan/scatter kernels.

__global__ __launch_bounds__(256) void k_csr(
    const unsigned int* __restrict__ scr, const int* __restrict__ gfill,
    const int* __restrict__ gbase, int N,
    int* __restrict__ rowp, int* __restrict__ col, float* __restrict__ dinv)
{
    __shared__ unsigned int stage[CAP];
    __shared__ int hist[128];
    __shared__ int offs[128];
    __shared__ int cur[128];
    int b = blockIdx.x, t = threadIdx.x;
    int cnt = gfill[b];
    if (cnt > CAP) cnt = CAP;
    int base = gbase[b];
    if (t < 128) hist[t] = 0;
    __syncthreads();
    for (int i = t; i < cnt; i += 256) {
        unsigned int p = scr[(size_t)b * CAP + i];
        stage[i] = p;
        atomicAdd(&hist[p >> 17], 1);
    }
    __syncthreads();
    if (t < 128) offs[t] = hist[t];
    __syncthreads();
    for (int off = 1; off < 128; off <<= 1) {
        int x = 0;
        if (t < 128 && t >= off) x = offs[t - off];
        __syncthreads();
        if (t < 128) offs[t] += x;
        __syncthreads();
    }
    if (t < 128) {
        int excl = offs[t] - hist[t];      // exclusive scan
        cur[t] = 0;
        int d = b * 128 + t;
        if (d < N) {
            rowp[d] = base + excl;
            dinv[d] = rsqrtf((float)(hist[t] + 1));   // +1 self-loop
        }
        offs[t] = excl;
    }
    __syncthreads();
    for (int i = t; i < cnt; i += 256) {
        unsigned int p = stage[i];
        int dl = (int)(p >> 17);
        int pos = offs[dl] + atomicAdd(&cur[dl], 1);
        col[base + pos] = (int)(p & 0x1FFFFu);
    }
}

// ---------------- small-table precompute: P = tab[R,64] @ Wseg[64,128] ----------------

__global__ __launch_bounds__(256) void k_ptab(
    const float* __restrict__ tab, const float* __restrict__ Wseg,
    float* __restrict__ P, int R)
{
    __shared__ float Wl[64][128];          // 32KB
    int t = threadIdx.x;
    for (int idx = t; idx < 64 * 128; idx += 256)
        Wl[idx >> 7][idx & 127] = Wseg[idx];
    __syncthreads();
    int cg = t & 31, ng = t >> 5;
    int r = blockIdx.x * 8 + ng;
    if (r >= R) return;
    const float* x = tab + (size_t)r * 64;
    float4 acc = make_float4(0.f, 0.f, 0.f, 0.f);
    #pragma unroll 8
    for (int k = 0; k < 64; ++k) {
        float xx = x[k];
        float4 w = *(const float4*)&Wl[k][cg * 4];
        acc.x += xx * w.x; acc.y += xx * w.y;
        acc.z += xx * w.z; acc.w += xx * w.w;
    }
    *(float4*)&P[(size_t)r * 128 + cg * 4] = acc;
}

// ---------------- layer 1 GEMM: h[n] = elem_emb[eid[n]]@W1c + Pcat[cid] + Psub[sid] ----

__global__ __launch_bounds__(256) void k_gemm1(
    const int* __restrict__ cid, const int* __restrict__ sid, const int* __restrict__ eid,
    const float* __restrict__ elem_t, const float* __restrict__ W1,
    const float* __restrict__ Pcat, const float* __restrict__ Psub,
    const float* __restrict__ dinv,
    unsigned short* __restrict__ hb, int N)
{
    __shared__ float Wl[64][128];          // 32KB
    int t = threadIdx.x;
    const float* Wc = W1 + 128 * 128;      // rows 128..191
    for (int idx = t; idx < 64 * 128; idx += 256)
        Wl[idx >> 7][idx & 127] = Wc[idx];
    __syncthreads();

    int cg = t & 31;
    int ng = t >> 5;
    int n0 = blockIdx.x << 6;

    const float* rp[8];
    #pragma unroll
    for (int i = 0; i < 8; ++i) {
        int n = n0 + ng + 8 * i;
        int id = eid[(n < N) ? n : 0];
        rp[i] = elem_t + (size_t)id * 64;
    }
    float4 acc[8];
    #pragma unroll
    for (int i = 0; i < 8; ++i) acc[i] = make_float4(0.f, 0.f, 0.f, 0.f);

    #pragma unroll 4
    for (int k4 = 0; k4 < 16; ++k4) {
        float4 xv[8];
        #pragma unroll
        for (int i = 0; i < 8; ++i)
            xv[i] = *(const float4*)(rp[i] + k4 * 4);
        #pragma unroll
        for (int kk = 0; kk < 4; ++kk) {
            float4 w = *(const float4*)&Wl[k4 * 4 + kk][cg * 4];
            #pragma unroll
            for (int i = 0; i < 8; ++i) {
                float xx = (kk == 0) ? xv[i].x : (kk == 1) ? xv[i].y
                         : (kk == 2) ? xv[i].z : xv[i].w;
                acc[i].x += xx * w.x;
                acc[i].y += xx * w.y;
                acc[i].z += xx * w.z;
                acc[i].w += xx * w.w;
            }
        }
    }
    #pragma unroll
    for (int i = 0; i < 8; ++i) {
        int n = n0 + ng + 8 * i;
        if (n < N) {
            float4 pc = *(const float4*)&Pcat[(size_t)cid[n] * 128 + cg * 4];
            float4 ps = *(const float4*)&Psub[(size_t)sid[n] * 128 + cg * 4];
            float s = dinv[n];
            uint2 p;
            p.x = pack2bf((acc[i].x + pc.x + ps.x) * s, (acc[i].y + pc.y + ps.y) * s);
            p.y = pack2bf((acc[i].z + pc.z + ps.z) * s, (acc[i].w + pc.w + ps.w) * s);
            *(uint2*)(hb + (size_t)n * 128 + cg * 4) = p;
        }
    }
}

// ---------------- layer 2 GEMM: y(bf16)[N,128] @ W2[128,64] ----------------

__global__ __launch_bounds__(256) void k_gemm2(
    const unsigned int* __restrict__ yb, const float* __restrict__ W2,
    const float* __restrict__ dinv,
    unsigned short* __restrict__ h2b, int N)
{
    __shared__ float Wl[128][64];          // 32KB
    int t = threadIdx.x;
    for (int idx = t; idx < 128 * 64; idx += 256)
        Wl[idx >> 6][idx & 63] = W2[idx];
    __syncthreads();

    int cg = t & 15;
    int ng = t >> 4;
    int n0 = blockIdx.x << 7;
    const unsigned int* rp[8];
    float4 acc[8];
    #pragma unroll
    for (int i = 0; i < 8; ++i) {
        acc[i] = make_float4(0.f, 0.f, 0.f, 0.f);
        int n = n0 + ng + 16 * i;
        rp[i] = yb + (size_t)((n < N) ? n : (N - 1)) * 64;
    }
    #pragma unroll 4
    for (int k4 = 0; k4 < 32; ++k4) {
        uint2 xv[8];
        #pragma unroll
        for (int i = 0; i < 8; ++i)
            xv[i] = *(const uint2*)(rp[i] + k4 * 2);
        #pragma unroll
        for (int kk = 0; kk < 4; ++kk) {
            float4 w = *(const float4*)&Wl[k4 * 4 + kk][cg * 4];
            #pragma unroll
            for (int i = 0; i < 8; ++i) {
                float xx = (kk == 0) ? bflo(xv[i].x) : (kk == 1) ? bfhi(xv[i].x)
                         : (kk == 2) ? bflo(xv[i].y) : bfhi(xv[i].y);
                acc[i].x += xx * w.x;
                acc[i].y += xx * w.y;
                acc[i].z += xx * w.z;
                acc[i].w += xx * w.w;
            }
        }
    }
    #pragma unroll
    for (int i = 0; i < 8; ++i) {
        int n = n0 + ng + 16 * i;
        if (n < N) {
            float s = dinv[n];
            uint2 p;
            p.x = pack2bf(acc[i].x * s, acc[i].y * s);
            p.y = pack2bf(acc[i].z * s, acc[i].w * s);
            *(uint2*)(h2b + (size_t)n * 64 + cg * 4) = p;
        }
    }
}

// ---------------- layer 1 aggregation: 1 wave per dst node, 2 bf16 cols/lane ----------------

__global__ __launch_bounds__(256) void k_agg1(
    const unsigned short* __restrict__ hb, const int* __restrict__ rowp,
    const int* __restrict__ col, const float* __restrict__ dinv,
    const float* __restrict__ b1, unsigned int* __restrict__ yb, int N)
{
    int wv = threadIdx.x >> 6;
    int lane = threadIdx.x & 63;
    int d = blockIdx.x * 4 + wv;
    if (d >= N) return;
    const unsigned int* hp = (const unsigned int*)hb;
    float dd = dinv[d];
    unsigned int su = hp[(size_t)d * 64 + lane];
    float ax0 = bflo(su), ay0 = bfhi(su);
    float ax1 = 0.f, ay1 = 0.f, ax2 = 0.f, ay2 = 0.f, ax3 = 0.f, ay3 = 0.f;
    float ax4 = 0.f, ay4 = 0.f, ax5 = 0.f, ay5 = 0.f, ax6 = 0.f, ay6 = 0.f;
    float ax7 = 0.f, ay7 = 0.f;
    int e = rowp[d], e1 = rowp[d + 1];
    for (; e + 8 <= e1; e += 8) {
        int s0 = col[e + 0], s1 = col[e + 1], s2 = col[e + 2], s3 = col[e + 3];
        int s4 = col[e + 4], s5 = col[e + 5], s6 = col[e + 6], s7 = col[e + 7];
        unsigned int u0 = hp[(size_t)s0 * 64 + lane];
        unsigned int u1 = hp[(size_t)s1 * 64 + lane];
        unsigned int u2 = hp[(size_t)s2 * 64 + lane];
        unsigned int u3 = hp[(size_t)s3 * 64 + lane];
        unsigned int u4 = hp[(size_t)s4 * 64 + lane];
        unsigned int u5 = hp[(size_t)s5 * 64 + lane];
        unsigned int u6 = hp[(size_t)s6 * 64 + lane];
        unsigned int u7 = hp[(size_t)s7 * 64 + lane];
        ax0 += bflo(u0); ay0 += bfhi(u0);
        ax1 += bflo(u1); ay1 += bfhi(u1);
        ax2 += bflo(u2); ay2 += bfhi(u2);
        ax3 += bflo(u3); ay3 += bfhi(u3);
        ax4 += bflo(u4); ay4 += bfhi(u4);
        ax5 += bflo(u5); ay5 += bfhi(u5);
        ax6 += bflo(u6); ay6 += bfhi(u6);
        ax7 += bflo(u7); ay7 += bfhi(u7);
    }
    for (; e < e1; ++e) {
        unsigned int u = hp[(size_t)col[e] * 64 + lane];
        ax0 += bflo(u); ay0 += bfhi(u);
    }
    float2 bb = *(const float2*)&b1[lane * 2];
    float rx = dd * (((ax0 + ax1) + (ax2 + ax3)) + ((ax4 + ax5) + (ax6 + ax7))) + bb.x;
    float ry = dd * (((ay0 + ay1) + (ay2 + ay3)) + ((ay4 + ay5) + (ay6 + ay7))) + bb.y;
    yb[(size_t)d * 64 + lane] = pack2bf(rx > 0.f ? rx : 0.f, ry > 0.f ? ry : 0.f);
}

// ---------------- layer 2 aggregation: 1 wave per dst node, 1 bf16 col/lane ----------------

__global__ __launch_bounds__(256) void k_agg2(
    const unsigned short* __restrict__ h2b, const int* __restrict__ rowp,
    const int* __restrict__ col, const float* __restrict__ dinv,
    const float* __restrict__ b2, float* __restrict__ out, int N)
{
    int wv = threadIdx.x >> 6;
    int lane = threadIdx.x & 63;
    int d = blockIdx.x * 4 + wv;
    if (d >= N) return;
    float dd = dinv[d];
    float a0 = __uint_as_float((unsigned int)h2b[(size_t)d * 64 + lane] << 16);
    float a1 = 0.f, a2 = 0.f, a3 = 0.f, a4 = 0.f, a5 = 0.f, a6 = 0.f, a7 = 0.f;
    int e = rowp[d], e1 = rowp[d + 1];
    for (; e + 8 <= e1; e += 8) {
        int s0 = col[e + 0], s1 = col[e + 1], s2 = col[e + 2], s3 = col[e + 3];
        int s4 = col[e + 4], s5 = col[e + 5], s6 = col[e + 6], s7 = col[e + 7];
        a0 += __uint_as_float((unsigned int)h2b[(size_t)s0 * 64 + lane] << 16);
        a1 += __uint_as_float((unsigned int)h2b[(size_t)s1 * 64 + lane] << 16);
        a2 += __uint_as_float((unsigned int)h2b[(size_t)s2 * 64 + lane] << 16);
        a3 += __uint_as_float((unsigned int)h2b[(size_t)s3 * 64 + lane] << 16);
        a4 += __uint_as_float((unsigned int)h2b[(size_t)s4 * 64 + lane] << 16);
        a5 += __uint_as_float((unsigned int)h2b[(size_t)s5 * 64 + lane] << 16);
        a6 += __uint_as_float((unsigned int)h2b[(size_t)s6 * 64 + lane] << 16);
        a7 += __uint_as_float((unsigned int)h2b[(size_t)s7 * 64 + lane] << 16);
    }
    for (; e < e1; ++e)
        a0 += __uint_as_float((unsigned int)h2b[(size_t)col[e] * 64 + lane] << 16);
    float v = dd * (((a0 + a1) + (a2 + a3)) + ((a4 + a5) + (a6 + a7))) + b2[lane];
    out[(size_t)d * 64 + lane] = v > 0.f ? v : 0.f;
}

// ---------------- launch ----------------

extern "C" void kernel_launch(void* const* d_in, const int* in_sizes, int n_in,
                              void* d_out, int out_size, void* d_ws, size_t ws_size,
                              hipStream_t stream) {
    const int*   cid    = (const int*)d_in[0];
    const int*   sid    = (const int*)d_in[1];
    const int*   eid    = (const int*)d_in[2];
    const int*   edge   = (const int*)d_in[3];
    const float* cat_t  = (const float*)d_in[4];
    const float* sub_t  = (const float*)d_in[5];
    const float* elem_t = (const float*)d_in[6];
    const float* W1     = (const float*)d_in[7];
    const float* b1     = (const float*)d_in[8];
    const float* W2     = (const float*)d_in[9];
    const float* b2     = (const float*)d_in[10];
    float* out = (float*)d_out;

    int N = in_sizes[0];
    int E = in_sizes[3] / 2;
    const int* src = edge;
    const int* dst = edge + E;

    int*   ws    = (int*)d_ws;
    float* dinv  = (float*)(ws + OFF_DINV);
    int*   rowp  = ws + OFF_ROWP;
    int*   col   = ws + OFF_COL;
    int*   gfill = ws + OFF_GFILL;
    int*   gbase = ws + OFF_GBASE;
    unsigned int* scr = (unsigned int*)(ws + OFF_SCR);
    unsigned short* hb = (unsigned short*)(ws + OFF_H);
    unsigned int*   yb = (unsigned int*)(ws + OFF_Y);
    float* Pcat = (float*)(ws + OFF_PCAT);
    float* Psub = (float*)(ws + OFF_PSUB);

    hipMemsetAsync(gfill, 0, NBUCK * sizeof(int), stream);

    // small-table premultiplies (independent of CSR build)
    k_ptab<<<125, 256, 0, stream>>>(cat_t, W1,            Pcat, 1000);
    k_ptab<<<625, 256, 0, stream>>>(sub_t, W1 + 64 * 128, Psub, 5000);

    // CSR build: bin -> scan -> in-bucket sort (emits rowp, col, dinv)
    k_bin<<<200, 256, 0, stream>>>(src, dst, E, gfill, scr);
    k_bscan<<<1, 256, 0, stream>>>(gfill, gbase, rowp, E);
    k_csr<<<NBUCK, 256, 0, stream>>>(scr, gfill, gbase, N, rowp, col, dinv);

    k_gemm1<<<(N + 63) / 64, 256, 0, stream>>>(cid, sid, eid, elem_t, W1, Pcat, Psub, dinv, hb, N);
    k_agg1<<<(N + 3) / 4, 256, 0, stream>>>(hb, rowp, col, dinv, b1, yb, N);
    k_gemm2<<<(N + 127) / 128, 256, 0, stream>>>(yb, W2, dinv, hb, N);
    k_agg2<<<(N + 3) / 4, 256, 0, stream>>>(hb, rowp, col, dinv, b2, out, N);
}

// Round 7
// 421.401 us; speedup vs baseline: 2.3322x; 1.0181x over previous
//
#include <hip/hip_runtime.h>

#define N_NODES 100000
#define EMB     64
#define H1      128
#define H2      64

#define BSHIFT  7
#define NBUCK   782            // ceil(100000 / 128)
#define CAP     3072           // max edges per bucket (mean 2048, sigma 45)

// workspace layout (4-byte elements), all 16B-aligned
#define OFF_DINV  0            // 100000 floats
#define OFF_ROWP  100004       // 100001 ints
#define OFF_COL   200008       // E ints
#define OFF_GFILL 1800008      // NBUCK ints
#define OFF_GBASE 1800792      // NBUCK+1 ints
#define OFF_SCR   1801576      // NBUCK*CAP uints (9.6MB)
#define OFF_H     4203880      // N*128 ushort (bf16 h; reused as h2 N*64)
#define OFF_Y     10603880     // N*64 uint (bf16 y pairs)
#define OFF_PCAT  17003880     // 1000*128 floats
#define OFF_PSUB  17131880     // 5000*128 floats

static __device__ __forceinline__ unsigned short f2bf(float f) {
    unsigned int u = __float_as_uint(f);
    unsigned int r = (u + 0x7fffu + ((u >> 16) & 1u)) >> 16;   // RNE
    return (unsigned short)r;
}
static __device__ __forceinline__ unsigned int pack2bf(float a, float b) {
    return (unsigned int)f2bf(a) | ((unsigned int)f2bf(b) << 16);
}
static __device__ __forceinline__ float bflo(unsigned int u) {
    return __uint_as_float(u << 16);
}
static __device__ __forceinline__ float bfhi(unsigned int u) {
    return __uint_as_float(u & 0xffff0000u);
}

// ---------------- CSR build pass 1: coarse binning (1024 thr for occupancy) ----------------

__global__ __launch_bounds__(1024) void k_bin(
    const int* __restrict__ src, const int* __restrict__ dst, int E,
    int* __restrict__ gfill, unsigned int* __restrict__ scr)
{
    __shared__ int hist[NBUCK];
    __shared__ int basec[NBUCK];
    int t = threadIdx.x;
    for (int i = t; i < NBUCK; i += 1024) hist[i] = 0;
    __syncthreads();
    int chunk = (E + gridDim.x - 1) / gridDim.x;
    int e0 = blockIdx.x * chunk;
    int e1 = min(e0 + chunk, E);
    for (int i = e0 + t; i < e1; i += 1024)
        atomicAdd(&hist[dst[i] >> BSHIFT], 1);
    __syncthreads();
    for (int b = t; b < NBUCK; b += 1024) {
        int c = hist[b];
        basec[b] = (c > 0) ? atomicAdd(&gfill[b], c) : 0;
        hist[b] = 0;                       // reuse as block-local cursor
    }
    __syncthreads();
    for (int i = e0 + t; i < e1; i += 1024) {
        int d = dst[i];
        int b = d >> BSHIFT;
        int slot = basec[b] + atomicAdd(&hist[b], 1);
        if (slot < CAP)
            scr[(size_t)b * CAP + slot] =
                ((unsigned int)(d & 127) << 17) | (unsigned int)src[i];
    }
}

// ---------------- CSR build pass 2: scan bucket totals ----------------

__global__ __launch_bounds__(256) void k_bscan(
    const int* __restrict__ gfill, int* __restrict__ gbase,
    int* __restrict__ rowp, int E)
{
    __shared__ int sh[256];
    int t = threadIdx.x;
    int v[4]; int s = 0;
    #pragma unroll
    for (int u = 0; u < 4; ++u) {
        int i = t * 4 + u;
        v[u] = (i < NBUCK) ? gfill[i] : 0;
        s += v[u];
    }
    sh[t] = s;
    __syncthreads();
    for (int off = 1; off < 256; off <<= 1) {
        int x = (t >= off) ? sh[t - off] : 0;
        __syncthreads();
        sh[t] += x;
        __syncthreads();
    }
    int run = (t == 0) ? 0 : sh[t - 1];
    #pragma unroll
    for (int u = 0; u < 4; ++u) {
        int i = t * 4 + u;
        if (i < NBUCK) gbase[i] = run;
        run += v[u];
    }
    if (t == 255) { gbase[NBUCK] = run; rowp[N_NODES] = E; }
}

// ---------------- CSR build pass 3: in-bucket counting sort (512 thr) ----------------

__global__ __launch_bounds__(512) void k_csr(
    const unsigned int* __restrict__ scr, const int* __restrict__ gfill,
    const int* __restrict__ gbase, int N,
    int* __restrict__ rowp, int* __restrict__ col, float* __restrict__ dinv)
{
    __shared__ unsigned int stage[CAP];
    __shared__ int hist[128];
    __shared__ int offs[128];
    __shared__ int cur[128];
    int b = blockIdx.x, t = threadIdx.x;
    int cnt = gfill[b];
    if (cnt > CAP) cnt = CAP;
    int base = gbase[b];
    if (t < 128) hist[t] = 0;
    __syncthreads();
    for (int i = t; i < cnt; i += 512) {
        unsigned int p = scr[(size_t)b * CAP + i];
        stage[i] = p;
        atomicAdd(&hist[p >> 17], 1);
    }
    __syncthreads();
    if (t < 128) offs[t] = hist[t];
    __syncthreads();
    for (int off = 1; off < 128; off <<= 1) {
        int x = 0;
        if (t < 128 && t >= off) x = offs[t - off];
        __syncthreads();
        if (t < 128) offs[t] += x;
        __syncthreads();
    }
    if (t < 128) {
        int excl = offs[t] - hist[t];      // exclusive scan
        cur[t] = 0;
        int d = b * 128 + t;
        if (d < N) {
            rowp[d] = base + excl;
            dinv[d] = rsqrtf((float)(hist[t] + 1));   // +1 self-loop
        }
        offs[t] = excl;
    }
    __syncthreads();
    for (int i = t; i < cnt; i += 512) {
        unsigned int p = stage[i];
        int dl = (int)(p >> 17);
        int pos = offs[dl] + atomicAdd(&cur[dl], 1);
        col[base + pos] = (int)(p & 0x1FFFFu);
    }
}

// ---------------- small-table precompute: P = tab[R,64] @ Wseg[64,128] ----------------

__global__ __launch_bounds__(256) void k_ptab(
    const float* __restrict__ tab, const float* __restrict__ Wseg,
    float* __restrict__ P, int R)
{
    __shared__ float Wl[64][128];          // 32KB
    int t = threadIdx.x;
    for (int idx = t; idx < 64 * 128; idx += 256)
        Wl[idx >> 7][idx & 127] = Wseg[idx];
    __syncthreads();
    int cg = t & 31, ng = t >> 5;
    int r = blockIdx.x * 8 + ng;
    if (r >= R) return;
    const float* x = tab + (size_t)r * 64;
    float4 acc = make_float4(0.f, 0.f, 0.f, 0.f);
    #pragma unroll 8
    for (int k = 0; k < 64; ++k) {
        float xx = x[k];
        float4 w = *(const float4*)&Wl[k][cg * 4];
        acc.x += xx * w.x; acc.y += xx * w.y;
        acc.z += xx * w.z; acc.w += xx * w.w;
    }
    *(float4*)&P[(size_t)r * 128 + cg * 4] = acc;
}

// ---------------- layer 1 GEMM: h[n] = elem_emb[eid[n]]@W1c + Pcat[cid] + Psub[sid] ----

__global__ __launch_bounds__(256) void k_gemm1(
    const int* __restrict__ cid, const int* __restrict__ sid, const int* __restrict__ eid,
    const float* __restrict__ elem_t, const float* __restrict__ W1,
    const float* __restrict__ Pcat, const float* __restrict__ Psub,
    const float* __restrict__ dinv,
    unsigned short* __restrict__ hb, int N)
{
    __shared__ float Wl[64][128];          // 32KB
    int t = threadIdx.x;
    const float* Wc = W1 + 128 * 128;      // rows 128..191
    for (int idx = t; idx < 64 * 128; idx += 256)
        Wl[idx >> 7][idx & 127] = Wc[idx];
    __syncthreads();

    int cg = t & 31;
    int ng = t >> 5;
    int n0 = blockIdx.x << 6;

    const float* rp[8];
    #pragma unroll
    for (int i = 0; i < 8; ++i) {
        int n = n0 + ng + 8 * i;
        int id = eid[(n < N) ? n : 0];
        rp[i] = elem_t + (size_t)id * 64;
    }
    float4 acc[8];
    #pragma unroll
    for (int i = 0; i < 8; ++i) acc[i] = make_float4(0.f, 0.f, 0.f, 0.f);

    #pragma unroll 4
    for (int k4 = 0; k4 < 16; ++k4) {
        float4 xv[8];
        #pragma unroll
        for (int i = 0; i < 8; ++i)
            xv[i] = *(const float4*)(rp[i] + k4 * 4);
        #pragma unroll
        for (int kk = 0; kk < 4; ++kk) {
            float4 w = *(const float4*)&Wl[k4 * 4 + kk][cg * 4];
            #pragma unroll
            for (int i = 0; i < 8; ++i) {
                float xx = (kk == 0) ? xv[i].x : (kk == 1) ? xv[i].y
                         : (kk == 2) ? xv[i].z : xv[i].w;
                acc[i].x += xx * w.x;
                acc[i].y += xx * w.y;
                acc[i].z += xx * w.z;
                acc[i].w += xx * w.w;
            }
        }
    }
    #pragma unroll
    for (int i = 0; i < 8; ++i) {
        int n = n0 + ng + 8 * i;
        if (n < N) {
            float4 pc = *(const float4*)&Pcat[(size_t)cid[n] * 128 + cg * 4];
            float4 ps = *(const float4*)&Psub[(size_t)sid[n] * 128 + cg * 4];
            float s = dinv[n];
            uint2 p;
            p.x = pack2bf((acc[i].x + pc.x + ps.x) * s, (acc[i].y + pc.y + ps.y) * s);
            p.y = pack2bf((acc[i].z + pc.z + ps.z) * s, (acc[i].w + pc.w + ps.w) * s);
            *(uint2*)(hb + (size_t)n * 128 + cg * 4) = p;
        }
    }
}

// ---------------- layer 2 GEMM: y(bf16)[N,128] @ W2[128,64] ----------------

__global__ __launch_bounds__(256) void k_gemm2(
    const unsigned int* __restrict__ yb, const float* __restrict__ W2,
    const float* __restrict__ dinv,
    unsigned short* __restrict__ h2b, int N)
{
    __shared__ float Wl[128][64];          // 32KB
    int t = threadIdx.x;
    for (int idx = t; idx < 128 * 64; idx += 256)
        Wl[idx >> 6][idx & 63] = W2[idx];
    __syncthreads();

    int cg = t & 15;
    int ng = t >> 4;
    int n0 = blockIdx.x << 7;
    const unsigned int* rp[8];
    float4 acc[8];
    #pragma unroll
    for (int i = 0; i < 8; ++i) {
        acc[i] = make_float4(0.f, 0.f, 0.f, 0.f);
        int n = n0 + ng + 16 * i;
        rp[i] = yb + (size_t)((n < N) ? n : (N - 1)) * 64;
    }
    #pragma unroll 4
    for (int k4 = 0; k4 < 32; ++k4) {
        uint2 xv[8];
        #pragma unroll
        for (int i = 0; i < 8; ++i)
            xv[i] = *(const uint2*)(rp[i] + k4 * 2);
        #pragma unroll
        for (int kk = 0; kk < 4; ++kk) {
            float4 w = *(const float4*)&Wl[k4 * 4 + kk][cg * 4];
            #pragma unroll
            for (int i = 0; i < 8; ++i) {
                float xx = (kk == 0) ? bflo(xv[i].x) : (kk == 1) ? bfhi(xv[i].x)
                         : (kk == 2) ? bflo(xv[i].y) : bfhi(xv[i].y);
                acc[i].x += xx * w.x;
                acc[i].y += xx * w.y;
                acc[i].z += xx * w.z;
                acc[i].w += xx * w.w;
            }
        }
    }
    #pragma unroll
    for (int i = 0; i < 8; ++i) {
        int n = n0 + ng + 16 * i;
        if (n < N) {
            float s = dinv[n];
            uint2 p;
            p.x = pack2bf(acc[i].x * s, acc[i].y * s);
            p.y = pack2bf(acc[i].z * s, acc[i].w * s);
            *(uint2*)(h2b + (size_t)n * 64 + cg * 4) = p;
        }
    }
}

// ---------------- layer 1 aggregation: 2 dst nodes per wave, 4 bf16 cols/lane ----------------
// Half-wave (32 lanes) per node; uint2 = 8B/lane per gather (256B row).
// Branchless predication: inactive lanes re-gather own row d (L1-hot) times 0.

__global__ __launch_bounds__(256) void k_agg1(
    const unsigned short* __restrict__ hb, const int* __restrict__ rowp,
    const int* __restrict__ col, const float* __restrict__ dinv,
    const float* __restrict__ b1, unsigned int* __restrict__ yb, int N, int E)
{
    int w = blockIdx.x * 4 + (threadIdx.x >> 6);
    int lane = threadIdx.x & 63;
    int half = lane >> 5, l5 = lane & 31;
    if (w * 2 >= N) return;
    int d = w * 2 + half;
    if (d >= N) d = N - 1;
    const unsigned int* hp = (const unsigned int*)hb;
    float dd = dinv[d];
    uint2 su = *(const uint2*)(hp + (size_t)d * 64 + 2 * l5);
    float a0 = bflo(su.x), a1 = bfhi(su.x), a2 = bflo(su.y), a3 = bfhi(su.y);
    float b0_ = 0.f, b1_ = 0.f, b2_ = 0.f, b3_ = 0.f;
    float c0_ = 0.f, c1_ = 0.f, c2_ = 0.f, c3_ = 0.f;
    float d0_ = 0.f, d1_ = 0.f, d2_ = 0.f, d3_ = 0.f;
    int e0 = rowp[d];
    int len = rowp[d + 1] - e0;
    int lo = __shfl_xor(len, 32);
    int lm = len > lo ? len : lo;
    int Emax = E - 1;
    int i = 0;
    for (; i + 8 <= lm; i += 8) {
        int c[8];
        #pragma unroll
        for (int k = 0; k < 8; ++k) c[k] = col[min(e0 + i + k, Emax)];
        #pragma unroll
        for (int k = 0; k < 8; ++k) {
            bool pr = (i + k) < len;
            int idx = pr ? c[k] : d;
            float m = pr ? 1.f : 0.f;
            uint2 u = *(const uint2*)(hp + (size_t)idx * 64 + 2 * l5);
            float* A = (k & 2) ? ((k & 1) ? &d0_ : &c0_) : ((k & 1) ? &b0_ : &a0);
            A[0] += m * bflo(u.x);
            A[1] += m * bfhi(u.x);
            A[2] += m * bflo(u.y);
            A[3] += m * bfhi(u.y);
        }
    }
    for (; i < lm; ++i) {
        bool pr = i < len;
        int idx = pr ? col[min(e0 + i, Emax)] : d;
        float m = pr ? 1.f : 0.f;
        uint2 u = *(const uint2*)(hp + (size_t)idx * 64 + 2 * l5);
        a0 += m * bflo(u.x); a1 += m * bfhi(u.x);
        a2 += m * bflo(u.y); a3 += m * bfhi(u.y);
    }
    float4 bb = *(const float4*)&b1[l5 * 4];
    float r0 = dd * ((a0 + b0_) + (c0_ + d0_)) + bb.x;
    float r1 = dd * ((a1 + b1_) + (c1_ + d1_)) + bb.y;
    float r2 = dd * ((a2 + b2_) + (c2_ + d2_)) + bb.z;
    float r3 = dd * ((a3 + b3_) + (c3_ + d3_)) + bb.w;
    uint2 p;
    p.x = pack2bf(r0 > 0.f ? r0 : 0.f, r1 > 0.f ? r1 : 0.f);
    p.y = pack2bf(r2 > 0.f ? r2 : 0.f, r3 > 0.f ? r3 : 0.f);
    *(uint2*)(yb + (size_t)d * 64 + 2 * l5) = p;
}

// ---------------- layer 2 aggregation: 2 dst nodes per wave, 2 bf16 cols/lane ----------------

__global__ __launch_bounds__(256) void k_agg2(
    const unsigned short* __restrict__ h2b, const int* __restrict__ rowp,
    const int* __restrict__ col, const float* __restrict__ dinv,
    const float* __restrict__ b2, float* __restrict__ out, int N, int E)
{
    int w = blockIdx.x * 4 + (threadIdx.x >> 6);
    int lane = threadIdx.x & 63;
    int half = lane >> 5, l5 = lane & 31;
    if (w * 2 >= N) return;
    int d = w * 2 + half;
    if (d >= N) d = N - 1;
    const unsigned int* hp = (const unsigned int*)h2b;   // 32 uints per row
    float dd = dinv[d];
    unsigned int su = hp[(size_t)d * 32 + l5];
    float a0 = bflo(su), a1 = bfhi(su);
    float b0_ = 0.f, b1_ = 0.f, c0_ = 0.f, c1_ = 0.f, d0_ = 0.f, d1_ = 0.f;
    float e0_ = 0.f, e1_ = 0.f, f0_ = 0.f, f1_ = 0.f, g0_ = 0.f, g1_ = 0.f;
    float h0_ = 0.f, h1_ = 0.f;
    int e0 = rowp[d];
    int len = rowp[d + 1] - e0;
    int lo = __shfl_xor(len, 32);
    int lm = len > lo ? len : lo;
    int Emax = E - 1;
    int i = 0;
    for (; i + 8 <= lm; i += 8) {
        int c[8];
        #pragma unroll
        for (int k = 0; k < 8; ++k) c[k] = col[min(e0 + i + k, Emax)];
        unsigned int u[8];
        #pragma unroll
        for (int k = 0; k < 8; ++k) {
            int idx = ((i + k) < len) ? c[k] : d;
            u[k] = hp[(size_t)idx * 32 + l5];
        }
        #pragma unroll
        for (int k = 0; k < 8; ++k) {
            float m = ((i + k) < len) ? 1.f : 0.f;
            float vx = m * bflo(u[k]), vy = m * bfhi(u[k]);
            switch (k) {
                case 0: a0 += vx; a1 += vy; break;
                case 1: b0_ += vx; b1_ += vy; break;
                case 2: c0_ += vx; c1_ += vy; break;
                case 3: d0_ += vx; d1_ += vy; break;
                case 4: e0_ += vx; e1_ += vy; break;
                case 5: f0_ += vx; f1_ += vy; break;
                case 6: g0_ += vx; g1_ += vy; break;
                default: h0_ += vx; h1_ += vy; break;
            }
        }
    }
    for (; i < lm; ++i) {
        bool pr = i < len;
        int idx = pr ? col[min(e0 + i, Emax)] : d;
        float m = pr ? 1.f : 0.f;
        unsigned int u = hp[(size_t)idx * 32 + l5];
        a0 += m * bflo(u); a1 += m * bfhi(u);
    }
    float2 bb = *(const float2*)&b2[l5 * 2];
    float v0 = dd * (((a0 + b0_) + (c0_ + d0_)) + ((e0_ + f0_) + (g0_ + h0_))) + bb.x;
    float v1 = dd * (((a1 + b1_) + (c1_ + d1_)) + ((e1_ + f1_) + (g1_ + h1_))) + bb.y;
    float2 r;
    r.x = v0 > 0.f ? v0 : 0.f;
    r.y = v1 > 0.f ? v1 : 0.f;
    *(float2*)&out[(size_t)d * 64 + 2 * l5] = r;
}

// ---------------- launch ----------------

extern "C" void kernel_launch(void* const* d_in, const int* in_sizes, int n_in,
                              void* d_out, int out_size, void* d_ws, size_t ws_size,
                              hipStream_t stream) {
    const int*   cid    = (const int*)d_in[0];
    const int*   sid    = (const int*)d_in[1];
    const int*   eid    = (const int*)d_in[2];
    const int*   edge   = (const int*)d_in[3];
    const float* cat_t  = (const float*)d_in[4];
    const float* sub_t  = (const float*)d_in[5];
    const float* elem_t = (const float*)d_in[6];
    const float* W1     = (const float*)d_in[7];
    const float* b1     = (const float*)d_in[8];
    const float* W2     = (const float*)d_in[9];
    const float* b2     = (const float*)d_in[10];
    float* out = (float*)d_out;

    int N = in_sizes[0];
    int E = in_sizes[3] / 2;
    const int* src = edge;
    const int* dst = edge + E;

    int*   ws    = (int*)d_ws;
    float* dinv  = (float*)(ws + OFF_DINV);
    int*   rowp  = ws + OFF_ROWP;
    int*   col   = ws + OFF_COL;
    int*   gfill = ws + OFF_GFILL;
    int*   gbase = ws + OFF_GBASE;
    unsigned int* scr = (unsigned int*)(ws + OFF_SCR);
    unsigned short* hb = (unsigned short*)(ws + OFF_H);
    unsigned int*   yb = (unsigned int*)(ws + OFF_Y);
    float* Pcat = (float*)(ws + OFF_PCAT);
    float* Psub = (float*)(ws + OFF_PSUB);

    hipMemsetAsync(gfill, 0, NBUCK * sizeof(int), stream);

    // small-table premultiplies (independent of CSR build)
    k_ptab<<<125, 256, 0, stream>>>(cat_t, W1,            Pcat, 1000);
    k_ptab<<<625, 256, 0, stream>>>(sub_t, W1 + 64 * 128, Psub, 5000);

    // CSR build: bin -> scan -> in-bucket sort (emits rowp, col, dinv)
    k_bin<<<200, 1024, 0, stream>>>(src, dst, E, gfill, scr);
    k_bscan<<<1, 256, 0, stream>>>(gfill, gbase, rowp, E);
    k_csr<<<NBUCK, 512, 0, stream>>>(scr, gfill, gbase, N, rowp, col, dinv);

    k_gemm1<<<(N + 63) / 64, 256, 0, stream>>>(cid, sid, eid, elem_t, W1, Pcat, Psub, dinv, hb, N);
    int aggblk = (N / 2 + 3) / 4;
    k_agg1<<<aggblk, 256, 0, stream>>>(hb, rowp, col, dinv, b1, yb, N, E);
    k_gemm2<<<(N + 127) / 128, 256, 0, stream>>>(yb, W2, dinv, hb, N);
    k_agg2<<<aggblk, 256, 0, stream>>>(hb, rowp, col, dinv, b2, out, N, E);
}

// Round 9
// 390.985 us; speedup vs baseline: 2.5136x; 1.0778x over previous
//
#include <hip/hip_runtime.h>

#define N_NODES 100000
#define EMB     64
#define H1      128
#define H2      64

#define BSHIFT  7
#define NBUCK   782            // ceil(100000 / 128)
#define CAP     3072           // max edges per bucket (mean 2048, sigma 45)

// workspace layout (4-byte elements), all 16B-aligned
#define OFF_DINV  0            // 100000 floats
#define OFF_ROWP  100004       // 100001 ints
#define OFF_COL   200008       // E ints
#define OFF_GFILL 1800008      // NBUCK ints
#define OFF_GBASE 1800792      // NBUCK+1 ints
#define OFF_SCR   1801576      // NBUCK*CAP uints (9.6MB)
#define OFF_H     4203880      // N*128 ushort (bf16 h; reused as h2 N*64)
#define OFF_Y     10603880     // N*64 uint (bf16 y pairs)
#define OFF_PCAT  17003880     // 1000*128 floats
#define OFF_PSUB  17131880     // 5000*128 floats

static __device__ __forceinline__ unsigned short f2bf(float f) {
    unsigned int u = __float_as_uint(f);
    unsigned int r = (u + 0x7fffu + ((u >> 16) & 1u)) >> 16;   // RNE
    return (unsigned short)r;
}
static __device__ __forceinline__ unsigned int pack2bf(float a, float b) {
    return (unsigned int)f2bf(a) | ((unsigned int)f2bf(b) << 16);
}
static __device__ __forceinline__ float bflo(unsigned int u) {
    return __uint_as_float(u << 16);
}
static __device__ __forceinline__ float bfhi(unsigned int u) {
    return __uint_as_float(u & 0xffff0000u);
}

// ---------------- CSR build pass 1: coarse binning (1024 thr) ----------------

__global__ __launch_bounds__(1024) void k_bin(
    const int* __restrict__ src, const int* __restrict__ dst, int E,
    int* __restrict__ gfill, unsigned int* __restrict__ scr)
{
    __shared__ int hist[NBUCK];
    __shared__ int basec[NBUCK];
    int t = threadIdx.x;
    for (int i = t; i < NBUCK; i += 1024) hist[i] = 0;
    __syncthreads();
    int chunk = (E + gridDim.x - 1) / gridDim.x;
    int e0 = blockIdx.x * chunk;
    int e1 = min(e0 + chunk, E);
    for (int i = e0 + t; i < e1; i += 1024)
        atomicAdd(&hist[dst[i] >> BSHIFT], 1);
    __syncthreads();
    for (int b = t; b < NBUCK; b += 1024) {
        int c = hist[b];
        basec[b] = (c > 0) ? atomicAdd(&gfill[b], c) : 0;
        hist[b] = 0;                       // reuse as block-local cursor
    }
    __syncthreads();
    for (int i = e0 + t; i < e1; i += 1024) {
        int d = dst[i];
        int b = d >> BSHIFT;
        int slot = basec[b] + atomicAdd(&hist[b], 1);
        if (slot < CAP)
            scr[(size_t)b * CAP + slot] =
                ((unsigned int)(d & 127) << 17) | (unsigned int)src[i];
    }
}

// ---------------- CSR build pass 2: scan bucket totals ----------------

__global__ __launch_bounds__(256) void k_bscan(
    const int* __restrict__ gfill, int* __restrict__ gbase,
    int* __restrict__ rowp, int E)
{
    __shared__ int sh[256];
    int t = threadIdx.x;
    int v[4]; int s = 0;
    #pragma unroll
    for (int u = 0; u < 4; ++u) {
        int i = t * 4 + u;
        v[u] = (i < NBUCK) ? gfill[i] : 0;
        s += v[u];
    }
    sh[t] = s;
    __syncthreads();
    for (int off = 1; off < 256; off <<= 1) {
        int x = (t >= off) ? sh[t - off] : 0;
        __syncthreads();
        sh[t] += x;
        __syncthreads();
    }
    int run = (t == 0) ? 0 : sh[t - 1];
    #pragma unroll
    for (int u = 0; u < 4; ++u) {
        int i = t * 4 + u;
        if (i < NBUCK) gbase[i] = run;
        run += v[u];
    }
    if (t == 255) { gbase[NBUCK] = run; rowp[N_NODES] = E; }
}

// ---------------- CSR build pass 3: in-bucket counting sort (512 thr) ----------------

__global__ __launch_bounds__(512) void k_csr(
    const unsigned int* __restrict__ scr, const int* __restrict__ gfill,
    const int* __restrict__ gbase, int N,
    int* __restrict__ rowp, int* __restrict__ col, float* __restrict__ dinv)
{
    __shared__ unsigned int stage[CAP];
    __shared__ int hist[128];
    __shared__ int offs[128];
    __shared__ int cur[128];
    int b = blockIdx.x, t = threadIdx.x;
    int cnt = gfill[b];
    if (cnt > CAP) cnt = CAP;
    int base = gbase[b];
    if (t < 128) hist[t] = 0;
    __syncthreads();
    for (int i = t; i < cnt; i += 512) {
        unsigned int p = scr[(size_t)b * CAP + i];
        stage[i] = p;
        atomicAdd(&hist[p >> 17], 1);
    }
    __syncthreads();
    if (t < 128) offs[t] = hist[t];
    __syncthreads();
    for (int off = 1; off < 128; off <<= 1) {
        int x = 0;
        if (t < 128 && t >= off) x = offs[t - off];
        __syncthreads();
        if (t < 128) offs[t] += x;
        __syncthreads();
    }
    if (t < 128) {
        int excl = offs[t] - hist[t];      // exclusive scan
        cur[t] = 0;
        int d = b * 128 + t;
        if (d < N) {
            rowp[d] = base + excl;
            dinv[d] = rsqrtf((float)(hist[t] + 1));   // +1 self-loop
        }
        offs[t] = excl;
    }
    __syncthreads();
    for (int i = t; i < cnt; i += 512) {
        unsigned int p = stage[i];
        int dl = (int)(p >> 17);
        int pos = offs[dl] + atomicAdd(&cur[dl], 1);
        col[base + pos] = (int)(p & 0x1FFFFu);
    }
}

// ---------------- small-table precompute: P = tab[R,64] @ Wseg[64,128] ----------------

__global__ __launch_bounds__(256) void k_ptab(
    const float* __restrict__ tab, const float* __restrict__ Wseg,
    float* __restrict__ P, int R)
{
    __shared__ float Wl[64][128];          // 32KB
    int t = threadIdx.x;
    for (int idx = t; idx < 64 * 128; idx += 256)
        Wl[idx >> 7][idx & 127] = Wseg[idx];
    __syncthreads();
    int cg = t & 31, ng = t >> 5;
    int r = blockIdx.x * 8 + ng;
    if (r >= R) return;
    const float* x = tab + (size_t)r * 64;
    float4 acc = make_float4(0.f, 0.f, 0.f, 0.f);
    #pragma unroll 8
    for (int k = 0; k < 64; ++k) {
        float xx = x[k];
        float4 w = *(const float4*)&Wl[k][cg * 4];
        acc.x += xx * w.x; acc.y += xx * w.y;
        acc.z += xx * w.z; acc.w += xx * w.w;
    }
    *(float4*)&P[(size_t)r * 128 + cg * 4] = acc;
}

// ---------------- layer 1 GEMM: h[n] = elem_emb[eid[n]]@W1c + Pcat[cid] + Psub[sid] ----

__global__ __launch_bounds__(256) void k_gemm1(
    const int* __restrict__ cid, const int* __restrict__ sid, const int* __restrict__ eid,
    const float* __restrict__ elem_t, const float* __restrict__ W1,
    const float* __restrict__ Pcat, const float* __restrict__ Psub,
    const float* __restrict__ dinv,
    unsigned short* __restrict__ hb, int N)
{
    __shared__ float Wl[64][128];          // 32KB
    int t = threadIdx.x;
    const float* Wc = W1 + 128 * 128;      // rows 128..191
    for (int idx = t; idx < 64 * 128; idx += 256)
        Wl[idx >> 7][idx & 127] = Wc[idx];
    __syncthreads();

    int cg = t & 31;
    int ng = t >> 5;
    int n0 = blockIdx.x << 6;

    const float* rp[8];
    #pragma unroll
    for (int i = 0; i < 8; ++i) {
        int n = n0 + ng + 8 * i;
        int id = eid[(n < N) ? n : 0];
        rp[i] = elem_t + (size_t)id * 64;
    }
    float4 acc[8];
    #pragma unroll
    for (int i = 0; i < 8; ++i) acc[i] = make_float4(0.f, 0.f, 0.f, 0.f);

    #pragma unroll 4
    for (int k4 = 0; k4 < 16; ++k4) {
        float4 xv[8];
        #pragma unroll
        for (int i = 0; i < 8; ++i)
            xv[i] = *(const float4*)(rp[i] + k4 * 4);
        #pragma unroll
        for (int kk = 0; kk < 4; ++kk) {
            float4 w = *(const float4*)&Wl[k4 * 4 + kk][cg * 4];
            #pragma unroll
            for (int i = 0; i < 8; ++i) {
                float xx = (kk == 0) ? xv[i].x : (kk == 1) ? xv[i].y
                         : (kk == 2) ? xv[i].z : xv[i].w;
                acc[i].x += xx * w.x;
                acc[i].y += xx * w.y;
                acc[i].z += xx * w.z;
                acc[i].w += xx * w.w;
            }
        }
    }
    #pragma unroll
    for (int i = 0; i < 8; ++i) {
        int n = n0 + ng + 8 * i;
        if (n < N) {
            float4 pc = *(const float4*)&Pcat[(size_t)cid[n] * 128 + cg * 4];
            float4 ps = *(const float4*)&Psub[(size_t)sid[n] * 128 + cg * 4];
            float s = dinv[n];
            uint2 p;
            p.x = pack2bf((acc[i].x + pc.x + ps.x) * s, (acc[i].y + pc.y + ps.y) * s);
            p.y = pack2bf((acc[i].z + pc.z + ps.z) * s, (acc[i].w + pc.w + ps.w) * s);
            *(uint2*)(hb + (size_t)n * 128 + cg * 4) = p;
        }
    }
}

// ---------------- layer 2 GEMM: y(bf16)[N,128] @ W2[128,64] ----------------

__global__ __launch_bounds__(256) void k_gemm2(
    const unsigned int* __restrict__ yb, const float* __restrict__ W2,
    const float* __restrict__ dinv,
    unsigned short* __restrict__ h2b, int N)
{
    __shared__ float Wl[128][64];          // 32KB
    int t = threadIdx.x;
    for (int idx = t; idx < 128 * 64; idx += 256)
        Wl[idx >> 6][idx & 63] = W2[idx];
    __syncthreads();

    int cg = t & 15;
    int ng = t >> 4;
    int n0 = blockIdx.x << 7;
    const unsigned int* rp[8];
    float4 acc[8];
    #pragma unroll
    for (int i = 0; i < 8; ++i) {
        acc[i] = make_float4(0.f, 0.f, 0.f, 0.f);
        int n = n0 + ng + 16 * i;
        rp[i] = yb + (size_t)((n < N) ? n : (N - 1)) * 64;
    }
    #pragma unroll 4
    for (int k4 = 0; k4 < 32; ++k4) {
        uint2 xv[8];
        #pragma unroll
        for (int i = 0; i < 8; ++i)
            xv[i] = *(const uint2*)(rp[i] + k4 * 2);
        #pragma unroll
        for (int kk = 0; kk < 4; ++kk) {
            float4 w = *(const float4*)&Wl[k4 * 4 + kk][cg * 4];
            #pragma unroll
            for (int i = 0; i < 8; ++i) {
                float xx = (kk == 0) ? bflo(xv[i].x) : (kk == 1) ? bfhi(xv[i].x)
                         : (kk == 2) ? bflo(xv[i].y) : bfhi(xv[i].y);
                acc[i].x += xx * w.x;
                acc[i].y += xx * w.y;
                acc[i].z += xx * w.z;
                acc[i].w += xx * w.w;
            }
        }
    }
    #pragma unroll
    for (int i = 0; i < 8; ++i) {
        int n = n0 + ng + 16 * i;
        if (n < N) {
            float s = dinv[n];
            uint2 p;
            p.x = pack2bf(acc[i].x * s, acc[i].y * s);
            p.y = pack2bf(acc[i].z * s, acc[i].w * s);
            *(uint2*)(h2b + (size_t)n * 64 + cg * 4) = p;
        }
    }
}

// ---------------- layer 1 aggregation: 1 wave per dst node, 8 predicated chains ----------------
// 64 lanes x uint (2 bf16) = full 256B row per instruction. No serial tail:
// batches of 8 with per-edge predication (masked edges re-gather own row, x0).

__global__ __launch_bounds__(256) void k_agg1(
    const unsigned short* __restrict__ hb, const int* __restrict__ rowp,
    const int* __restrict__ col, const float* __restrict__ dinv,
    const float* __restrict__ b1, unsigned int* __restrict__ yb, int N)
{
    int wv = threadIdx.x >> 6;
    int lane = threadIdx.x & 63;
    int d = blockIdx.x * 4 + wv;
    if (d >= N) return;
    const unsigned int* hp = (const unsigned int*)hb;   // 64 uints per row
    float dd = dinv[d];
    unsigned int su = hp[(size_t)d * 64 + lane];
    float ax0 = bflo(su), ay0 = bfhi(su);
    float ax1 = 0.f, ay1 = 0.f, ax2 = 0.f, ay2 = 0.f, ax3 = 0.f, ay3 = 0.f;
    float ax4 = 0.f, ay4 = 0.f, ax5 = 0.f, ay5 = 0.f, ax6 = 0.f, ay6 = 0.f;
    float ax7 = 0.f, ay7 = 0.f;
    int e0 = rowp[d];
    int len = rowp[d + 1] - e0;
    for (int i = 0; i < len; i += 8) {
        int c[8];
        #pragma unroll
        for (int k = 0; k < 8; ++k)
            c[k] = col[(i + k) < len ? (e0 + i + k) : e0];
        #pragma unroll
        for (int k = 0; k < 8; ++k) {
            bool pr = (i + k) < len;
            int idx = pr ? c[k] : d;
            float m = pr ? 1.f : 0.f;
            unsigned int u = hp[(size_t)idx * 64 + lane];
            float vx = m * bflo(u), vy = m * bfhi(u);
            switch (k) {
                case 0: ax0 += vx; ay0 += vy; break;
                case 1: ax1 += vx; ay1 += vy; break;
                case 2: ax2 += vx; ay2 += vy; break;
                case 3: ax3 += vx; ay3 += vy; break;
                case 4: ax4 += vx; ay4 += vy; break;
                case 5: ax5 += vx; ay5 += vy; break;
                case 6: ax6 += vx; ay6 += vy; break;
                default: ax7 += vx; ay7 += vy; break;
            }
        }
    }
    float2 bb = *(const float2*)&b1[lane * 2];
    float rx = dd * (((ax0 + ax1) + (ax2 + ax3)) + ((ax4 + ax5) + (ax6 + ax7))) + bb.x;
    float ry = dd * (((ay0 + ay1) + (ay2 + ay3)) + ((ay4 + ay5) + (ay6 + ay7))) + bb.y;
    yb[(size_t)d * 64 + lane] = pack2bf(rx > 0.f ? rx : 0.f, ry > 0.f ? ry : 0.f);
}

// ---------------- layer 2 aggregation: 1 wave per dst node, 8 predicated chains ----------------

__global__ __launch_bounds__(256) void k_agg2(
    const unsigned short* __restrict__ h2b, const int* __restrict__ rowp,
    const int* __restrict__ col, const float* __restrict__ dinv,
    const float* __restrict__ b2, float* __restrict__ out, int N)
{
    int wv = threadIdx.x >> 6;
    int lane = threadIdx.x & 63;
    int d = blockIdx.x * 4 + wv;
    if (d >= N) return;
    float dd = dinv[d];
    float a0 = __uint_as_float((unsigned int)h2b[(size_t)d * 64 + lane] << 16);
    float a1 = 0.f, a2 = 0.f, a3 = 0.f, a4 = 0.f, a5 = 0.f, a6 = 0.f, a7 = 0.f;
    int e0 = rowp[d];
    int len = rowp[d + 1] - e0;
    for (int i = 0; i < len; i += 8) {
        int c[8];
        #pragma unroll
        for (int k = 0; k < 8; ++k)
            c[k] = col[(i + k) < len ? (e0 + i + k) : e0];
        #pragma unroll
        for (int k = 0; k < 8; ++k) {
            bool pr = (i + k) < len;
            int idx = pr ? c[k] : d;
            float m = pr ? 1.f : 0.f;
            float v = m * __uint_as_float((unsigned int)h2b[(size_t)idx * 64 + lane] << 16);
            switch (k) {
                case 0: a0 += v; break;
                case 1: a1 += v; break;
                case 2: a2 += v; break;
                case 3: a3 += v; break;
                case 4: a4 += v; break;
                case 5: a5 += v; break;
                case 6: a6 += v; break;
                default: a7 += v; break;
            }
        }
    }
    float v = dd * (((a0 + a1) + (a2 + a3)) + ((a4 + a5) + (a6 + a7))) + b2[lane];
    out[(size_t)d * 64 + lane] = v > 0.f ? v : 0.f;
}

// ---------------- launch ----------------

extern "C" void kernel_launch(void* const* d_in, const int* in_sizes, int n_in,
                              void* d_out, int out_size, void* d_ws, size_t ws_size,
                              hipStream_t stream) {
    const int*   cid    = (const int*)d_in[0];
    const int*   sid    = (const int*)d_in[1];
    const int*   eid    = (const int*)d_in[2];
    const int*   edge   = (const int*)d_in[3];
    const float* cat_t  = (const float*)d_in[4];
    const float* sub_t  = (const float*)d_in[5];
    const float* elem_t = (const float*)d_in[6];
    const float* W1     = (const float*)d_in[7];
    const float* b1     = (const float*)d_in[8];
    const float* W2     = (const float*)d_in[9];
    const float* b2     = (const float*)d_in[10];
    float* out = (float*)d_out;

    int N = in_sizes[0];
    int E = in_sizes[3] / 2;
    const int* src = edge;
    const int* dst = edge + E;

    int*   ws    = (int*)d_ws;
    float* dinv  = (float*)(ws + OFF_DINV);
    int*   rowp  = ws + OFF_ROWP;
    int*   col   = ws + OFF_COL;
    int*   gfill = ws + OFF_GFILL;
    int*   gbase = ws + OFF_GBASE;
    unsigned int* scr = (unsigned int*)(ws + OFF_SCR);
    unsigned short* hb = (unsigned short*)(ws + OFF_H);
    unsigned int*   yb = (unsigned int*)(ws + OFF_Y);
    float* Pcat = (float*)(ws + OFF_PCAT);
    float* Psub = (float*)(ws + OFF_PSUB);

    hipMemsetAsync(gfill, 0, NBUCK * sizeof(int), stream);

    // small-table premultiplies (independent of CSR build)
    k_ptab<<<125, 256, 0, stream>>>(cat_t, W1,            Pcat, 1000);
    k_ptab<<<625, 256, 0, stream>>>(sub_t, W1 + 64 * 128, Psub, 5000);

    // CSR build: bin -> scan -> in-bucket sort (emits rowp, col, dinv)
    k_bin<<<200, 1024, 0, stream>>>(src, dst, E, gfill, scr);
    k_bscan<<<1, 256, 0, stream>>>(gfill, gbase, rowp, E);
    k_csr<<<NBUCK, 512, 0, stream>>>(scr, gfill, gbase, N, rowp, col, dinv);

    k_gemm1<<<(N + 63) / 64, 256, 0, stream>>>(cid, sid, eid, elem_t, W1, Pcat, Psub, dinv, hb, N);
    k_agg1<<<(N + 3) / 4, 256, 0, stream>>>(hb, rowp, col, dinv, b1, yb, N);
    k_gemm2<<<(N + 127) / 128, 256, 0, stream>>>(yb, W2, dinv, hb, N);
    k_agg2<<<(N + 3) / 4, 256, 0, stream>>>(hb, rowp, col, dinv, b2, out, N);
}

// Round 10
// 386.294 us; speedup vs baseline: 2.5441x; 1.0121x over previous
//
#include <hip/hip_runtime.h>

#define N_NODES 100000
#define EMB     64
#define H1      128
#define H2      64

#define BSHIFT  7
#define NBUCK   782            // ceil(100000 / 128)
#define CAP     3072           // max edges per bucket (mean 2048, sigma 45)

// workspace layout (4-byte elements), all 16B-aligned
#define OFF_DINV  0            // 100000 floats
#define OFF_ROWP  100004       // 100001 ints
#define OFF_COL   200008       // E ints
#define OFF_GFILL 1800008      // NBUCK ints
#define OFF_GBASE 1800792      // NBUCK+1 ints
#define OFF_SCR   1801576      // NBUCK*CAP uints (9.6MB)
#define OFF_H     4203880      // N*128 ushort (bf16 h; reused as h2 N*64)
#define OFF_Y     10603880     // N*64 uint (bf16 y pairs)
#define OFF_PCAT  17003880     // 1000*128 floats
#define OFF_PSUB  17131880     // 5000*128 floats

static __device__ __forceinline__ unsigned short f2bf(float f) {
    unsigned int u = __float_as_uint(f);
    unsigned int r = (u + 0x7fffu + ((u >> 16) & 1u)) >> 16;   // RNE
    return (unsigned short)r;
}
static __device__ __forceinline__ unsigned int pack2bf(float a, float b) {
    return (unsigned int)f2bf(a) | ((unsigned int)f2bf(b) << 16);
}
static __device__ __forceinline__ float bflo(unsigned int u) {
    return __uint_as_float(u << 16);
}
static __device__ __forceinline__ float bfhi(unsigned int u) {
    return __uint_as_float(u & 0xffff0000u);
}

// ---------------- CSR build pass 1: coarse binning (1024 thr) ----------------

__global__ __launch_bounds__(1024) void k_bin(
    const int* __restrict__ src, const int* __restrict__ dst, int E,
    int* __restrict__ gfill, unsigned int* __restrict__ scr)
{
    __shared__ int hist[NBUCK];
    __shared__ int basec[NBUCK];
    int t = threadIdx.x;
    for (int i = t; i < NBUCK; i += 1024) hist[i] = 0;
    __syncthreads();
    int chunk = (E + gridDim.x - 1) / gridDim.x;
    int e0 = blockIdx.x * chunk;
    int e1 = min(e0 + chunk, E);
    for (int i = e0 + t; i < e1; i += 1024)
        atomicAdd(&hist[dst[i] >> BSHIFT], 1);
    __syncthreads();
    for (int b = t; b < NBUCK; b += 1024) {
        int c = hist[b];
        basec[b] = (c > 0) ? atomicAdd(&gfill[b], c) : 0;
        hist[b] = 0;                       // reuse as block-local cursor
    }
    __syncthreads();
    for (int i = e0 + t; i < e1; i += 1024) {
        int d = dst[i];
        int b = d >> BSHIFT;
        int slot = basec[b] + atomicAdd(&hist[b], 1);
        if (slot < CAP)
            scr[(size_t)b * CAP + slot] =
                ((unsigned int)(d & 127) << 17) | (unsigned int)src[i];
    }
}

// ---------------- CSR build pass 2: scan bucket totals ----------------

__global__ __launch_bounds__(256) void k_bscan(
    const int* __restrict__ gfill, int* __restrict__ gbase,
    int* __restrict__ rowp, int E)
{
    __shared__ int sh[256];
    int t = threadIdx.x;
    int v[4]; int s = 0;
    #pragma unroll
    for (int u = 0; u < 4; ++u) {
        int i = t * 4 + u;
        v[u] = (i < NBUCK) ? gfill[i] : 0;
        s += v[u];
    }
    sh[t] = s;
    __syncthreads();
    for (int off = 1; off < 256; off <<= 1) {
        int x = (t >= off) ? sh[t - off] : 0;
        __syncthreads();
        sh[t] += x;
        __syncthreads();
    }
    int run = (t == 0) ? 0 : sh[t - 1];
    #pragma unroll
    for (int u = 0; u < 4; ++u) {
        int i = t * 4 + u;
        if (i < NBUCK) gbase[i] = run;
        run += v[u];
    }
    if (t == 255) { gbase[NBUCK] = run; rowp[N_NODES] = E; }
}

// ---------------- CSR build pass 3: in-bucket counting sort (512 thr) ----------------

__global__ __launch_bounds__(512) void k_csr(
    const unsigned int* __restrict__ scr, const int* __restrict__ gfill,
    const int* __restrict__ gbase, int N,
    int* __restrict__ rowp, int* __restrict__ col, float* __restrict__ dinv)
{
    __shared__ unsigned int stage[CAP];
    __shared__ int hist[128];
    __shared__ int offs[128];
    __shared__ int cur[128];
    int b = blockIdx.x, t = threadIdx.x;
    int cnt = gfill[b];
    if (cnt > CAP) cnt = CAP;
    int base = gbase[b];
    if (t < 128) hist[t] = 0;
    __syncthreads();
    for (int i = t; i < cnt; i += 512) {
        unsigned int p = scr[(size_t)b * CAP + i];
        stage[i] = p;
        atomicAdd(&hist[p >> 17], 1);
    }
    __syncthreads();
    if (t < 128) offs[t] = hist[t];
    __syncthreads();
    for (int off = 1; off < 128; off <<= 1) {
        int x = 0;
        if (t < 128 && t >= off) x = offs[t - off];
        __syncthreads();
        if (t < 128) offs[t] += x;
        __syncthreads();
    }
    if (t < 128) {
        int excl = offs[t] - hist[t];      // exclusive scan
        cur[t] = 0;
        int d = b * 128 + t;
        if (d < N) {
            rowp[d] = base + excl;
            dinv[d] = rsqrtf((float)(hist[t] + 1));   // +1 self-loop
        }
        offs[t] = excl;
    }
    __syncthreads();
    for (int i = t; i < cnt; i += 512) {
        unsigned int p = stage[i];
        int dl = (int)(p >> 17);
        int pos = offs[dl] + atomicAdd(&cur[dl], 1);
        col[base + pos] = (int)(p & 0x1FFFFu);
    }
}

// ---------------- small-table precompute: P = tab[R,64] @ Wseg[64,128] ----------------

__global__ __launch_bounds__(256) void k_ptab(
    const float* __restrict__ tab, const float* __restrict__ Wseg,
    float* __restrict__ P, int R)
{
    __shared__ float Wl[64][128];          // 32KB
    int t = threadIdx.x;
    for (int idx = t; idx < 64 * 128; idx += 256)
        Wl[idx >> 7][idx & 127] = Wseg[idx];
    __syncthreads();
    int cg = t & 31, ng = t >> 5;
    int r = blockIdx.x * 8 + ng;
    if (r >= R) return;
    const float* x = tab + (size_t)r * 64;
    float4 acc = make_float4(0.f, 0.f, 0.f, 0.f);
    #pragma unroll 8
    for (int k = 0; k < 64; ++k) {
        float xx = x[k];
        float4 w = *(const float4*)&Wl[k][cg * 4];
        acc.x += xx * w.x; acc.y += xx * w.y;
        acc.z += xx * w.z; acc.w += xx * w.w;
    }
    *(float4*)&P[(size_t)r * 128 + cg * 4] = acc;
}

// ---------------- layer 1 GEMM: h[n] = elem_emb[eid[n]]@W1c + Pcat[cid] + Psub[sid] ----

__global__ __launch_bounds__(256) void k_gemm1(
    const int* __restrict__ cid, const int* __restrict__ sid, const int* __restrict__ eid,
    const float* __restrict__ elem_t, const float* __restrict__ W1,
    const float* __restrict__ Pcat, const float* __restrict__ Psub,
    const float* __restrict__ dinv,
    unsigned short* __restrict__ hb, int N)
{
    __shared__ float Wl[64][128];          // 32KB
    int t = threadIdx.x;
    const float* Wc = W1 + 128 * 128;      // rows 128..191
    for (int idx = t; idx < 64 * 128; idx += 256)
        Wl[idx >> 7][idx & 127] = Wc[idx];
    __syncthreads();

    int cg = t & 31;
    int ng = t >> 5;
    int n0 = blockIdx.x << 6;

    const float* rp[8];
    #pragma unroll
    for (int i = 0; i < 8; ++i) {
        int n = n0 + ng + 8 * i;
        int id = eid[(n < N) ? n : 0];
        rp[i] = elem_t + (size_t)id * 64;
    }
    float4 acc[8];
    #pragma unroll
    for (int i = 0; i < 8; ++i) acc[i] = make_float4(0.f, 0.f, 0.f, 0.f);

    #pragma unroll 4
    for (int k4 = 0; k4 < 16; ++k4) {
        float4 xv[8];
        #pragma unroll
        for (int i = 0; i < 8; ++i)
            xv[i] = *(const float4*)(rp[i] + k4 * 4);
        #pragma unroll
        for (int kk = 0; kk < 4; ++kk) {
            float4 w = *(const float4*)&Wl[k4 * 4 + kk][cg * 4];
            #pragma unroll
            for (int i = 0; i < 8; ++i) {
                float xx = (kk == 0) ? xv[i].x : (kk == 1) ? xv[i].y
                         : (kk == 2) ? xv[i].z : xv[i].w;
                acc[i].x += xx * w.x;
                acc[i].y += xx * w.y;
                acc[i].z += xx * w.z;
                acc[i].w += xx * w.w;
            }
        }
    }
    #pragma unroll
    for (int i = 0; i < 8; ++i) {
        int n = n0 + ng + 8 * i;
        if (n < N) {
            float4 pc = *(const float4*)&Pcat[(size_t)cid[n] * 128 + cg * 4];
            float4 ps = *(const float4*)&Psub[(size_t)sid[n] * 128 + cg * 4];
            float s = dinv[n];
            uint2 p;
            p.x = pack2bf((acc[i].x + pc.x + ps.x) * s, (acc[i].y + pc.y + ps.y) * s);
            p.y = pack2bf((acc[i].z + pc.z + ps.z) * s, (acc[i].w + pc.w + ps.w) * s);
            *(uint2*)(hb + (size_t)n * 128 + cg * 4) = p;
        }
    }
}

// ---------------- layer 2 GEMM: y(bf16)[N,128] @ W2[128,64] ----------------

__global__ __launch_bounds__(256) void k_gemm2(
    const unsigned int* __restrict__ yb, const float* __restrict__ W2,
    const float* __restrict__ dinv,
    unsigned short* __restrict__ h2b, int N)
{
    __shared__ float Wl[128][64];          // 32KB
    int t = threadIdx.x;
    for (int idx = t; idx < 128 * 64; idx += 256)
        Wl[idx >> 6][idx & 63] = W2[idx];
    __syncthreads();

    int cg = t & 15;
    int ng = t >> 4;
    int n0 = blockIdx.x << 7;
    const unsigned int* rp[8];
    float4 acc[8];
    #pragma unroll
    for (int i = 0; i < 8; ++i) {
        acc[i] = make_float4(0.f, 0.f, 0.f, 0.f);
        int n = n0 + ng + 16 * i;
        rp[i] = yb + (size_t)((n < N) ? n : (N - 1)) * 64;
    }
    #pragma unroll 4
    for (int k4 = 0; k4 < 32; ++k4) {
        uint2 xv[8];
        #pragma unroll
        for (int i = 0; i < 8; ++i)
            xv[i] = *(const uint2*)(rp[i] + k4 * 2);
        #pragma unroll
        for (int kk = 0; kk < 4; ++kk) {
            float4 w = *(const float4*)&Wl[k4 * 4 + kk][cg * 4];
            #pragma unroll
            for (int i = 0; i < 8; ++i) {
                float xx = (kk == 0) ? bflo(xv[i].x) : (kk == 1) ? bfhi(xv[i].x)
                         : (kk == 2) ? bflo(xv[i].y) : bfhi(xv[i].y);
                acc[i].x += xx * w.x;
                acc[i].y += xx * w.y;
                acc[i].z += xx * w.z;
                acc[i].w += xx * w.w;
            }
        }
    }
    #pragma unroll
    for (int i = 0; i < 8; ++i) {
        int n = n0 + ng + 16 * i;
        if (n < N) {
            float s = dinv[n];
            uint2 p;
            p.x = pack2bf(acc[i].x * s, acc[i].y * s);
            p.y = pack2bf(acc[i].z * s, acc[i].w * s);
            *(uint2*)(h2b + (size_t)n * 64 + cg * 4) = p;
        }
    }
}

// ---------------- layer 1 aggregation: 2 dst nodes per wave (half-wave x uint2) ----------
// 32 lanes x 8B = 256B row; one gather instruction serves 2 edges. 4 chains of
// 4 NAMED accumulators (switch(k) keeps them in registers — no scratch).

__global__ __launch_bounds__(256) void k_agg1(
    const unsigned short* __restrict__ hb, const int* __restrict__ rowp,
    const int* __restrict__ col, const float* __restrict__ dinv,
    const float* __restrict__ b1, unsigned int* __restrict__ yb, int N)
{
    int w = blockIdx.x * 4 + (threadIdx.x >> 6);
    int lane = threadIdx.x & 63;
    int half = lane >> 5, l5 = lane & 31;
    int d0 = w * 2;
    if (d0 >= N) return;
    int d = d0 + half;
    if (d >= N) d = N - 1;
    const unsigned int* hp = (const unsigned int*)hb;   // 64 uints per row
    float dd = dinv[d];
    unsigned base = ((unsigned)d << 6) + (l5 << 1);
    uint2 su = *(const uint2*)(hp + base);
    float s00 = bflo(su.x), s01 = bfhi(su.x), s02 = bflo(su.y), s03 = bfhi(su.y);
    float s10 = 0.f, s11 = 0.f, s12 = 0.f, s13 = 0.f;
    float s20 = 0.f, s21 = 0.f, s22 = 0.f, s23 = 0.f;
    float s30 = 0.f, s31 = 0.f, s32 = 0.f, s33 = 0.f;
    int eb = rowp[d];
    int len = rowp[d + 1] - eb;
    int lo = __shfl_xor(len, 32);
    int lm = len > lo ? len : lo;
    for (int i = 0; i < lm; i += 4) {
        int cc[4];
        #pragma unroll
        for (int k = 0; k < 4; ++k)
            cc[k] = col[(i + k) < len ? (eb + i + k) : 0];
        #pragma unroll
        for (int k = 0; k < 4; ++k) {
            bool pr = (i + k) < len;
            int idx = pr ? cc[k] : d;
            float m = pr ? 1.f : 0.f;
            uint2 u = *(const uint2*)(hp + (((unsigned)idx) << 6) + (l5 << 1));
            float vx = m * bflo(u.x), vy = m * bfhi(u.x);
            float vz = m * bflo(u.y), vw = m * bfhi(u.y);
            switch (k) {
                case 0: s00 += vx; s01 += vy; s02 += vz; s03 += vw; break;
                case 1: s10 += vx; s11 += vy; s12 += vz; s13 += vw; break;
                case 2: s20 += vx; s21 += vy; s22 += vz; s23 += vw; break;
                default: s30 += vx; s31 += vy; s32 += vz; s33 += vw; break;
            }
        }
    }
    float4 bb = *(const float4*)&b1[l5 * 4];
    float r0 = dd * ((s00 + s10) + (s20 + s30)) + bb.x;
    float r1 = dd * ((s01 + s11) + (s21 + s31)) + bb.y;
    float r2 = dd * ((s02 + s12) + (s22 + s32)) + bb.z;
    float r3 = dd * ((s03 + s13) + (s23 + s33)) + bb.w;
    uint2 p;
    p.x = pack2bf(r0 > 0.f ? r0 : 0.f, r1 > 0.f ? r1 : 0.f);
    p.y = pack2bf(r2 > 0.f ? r2 : 0.f, r3 > 0.f ? r3 : 0.f);
    *(uint2*)(yb + base) = p;
}

// ---------------- layer 2 aggregation: 2 dst nodes per wave (half-wave x uint) ----------

__global__ __launch_bounds__(256) void k_agg2(
    const unsigned short* __restrict__ h2b, const int* __restrict__ rowp,
    const int* __restrict__ col, const float* __restrict__ dinv,
    const float* __restrict__ b2, float* __restrict__ out, int N)
{
    int w = blockIdx.x * 4 + (threadIdx.x >> 6);
    int lane = threadIdx.x & 63;
    int half = lane >> 5, l5 = lane & 31;
    int d0 = w * 2;
    if (d0 >= N) return;
    int d = d0 + half;
    if (d >= N) d = N - 1;
    const unsigned int* hp = (const unsigned int*)h2b;  // 32 uints per row
    float dd = dinv[d];
    unsigned base = ((unsigned)d << 5) + l5;
    unsigned su = hp[base];
    float s00 = bflo(su), s01 = bfhi(su);
    float s10 = 0.f, s11 = 0.f, s20 = 0.f, s21 = 0.f, s30 = 0.f, s31 = 0.f;
    float s40 = 0.f, s41 = 0.f, s50 = 0.f, s51 = 0.f, s60 = 0.f, s61 = 0.f;
    float s70 = 0.f, s71 = 0.f;
    int eb = rowp[d];
    int len = rowp[d + 1] - eb;
    int lo = __shfl_xor(len, 32);
    int lm = len > lo ? len : lo;
    for (int i = 0; i < lm; i += 8) {
        int cc[8];
        #pragma unroll
        for (int k = 0; k < 8; ++k)
            cc[k] = col[(i + k) < len ? (eb + i + k) : 0];
        #pragma unroll
        for (int k = 0; k < 8; ++k) {
            bool pr = (i + k) < len;
            int idx = pr ? cc[k] : d;
            float m = pr ? 1.f : 0.f;
            unsigned u = hp[(((unsigned)idx) << 5) + l5];
            float vx = m * bflo(u), vy = m * bfhi(u);
            switch (k) {
                case 0: s00 += vx; s01 += vy; break;
                case 1: s10 += vx; s11 += vy; break;
                case 2: s20 += vx; s21 += vy; break;
                case 3: s30 += vx; s31 += vy; break;
                case 4: s40 += vx; s41 += vy; break;
                case 5: s50 += vx; s51 += vy; break;
                case 6: s60 += vx; s61 += vy; break;
                default: s70 += vx; s71 += vy; break;
            }
        }
    }
    float2 bb = *(const float2*)&b2[l5 * 2];
    float v0 = dd * (((s00 + s10) + (s20 + s30)) + ((s40 + s50) + (s60 + s70))) + bb.x;
    float v1 = dd * (((s01 + s11) + (s21 + s31)) + ((s41 + s51) + (s61 + s71))) + bb.y;
    float2 r;
    r.x = v0 > 0.f ? v0 : 0.f;
    r.y = v1 > 0.f ? v1 : 0.f;
    *(float2*)&out[((size_t)d << 6) + (l5 << 1)] = r;
}

// ---------------- launch ----------------

extern "C" void kernel_launch(void* const* d_in, const int* in_sizes, int n_in,
                              void* d_out, int out_size, void* d_ws, size_t ws_size,
                              hipStream_t stream) {
    const int*   cid    = (const int*)d_in[0];
    const int*   sid    = (const int*)d_in[1];
    const int*   eid    = (const int*)d_in[2];
    const int*   edge   = (const int*)d_in[3];
    const float* cat_t  = (const float*)d_in[4];
    const float* sub_t  = (const float*)d_in[5];
    const float* elem_t = (const float*)d_in[6];
    const float* W1     = (const float*)d_in[7];
    const float* b1     = (const float*)d_in[8];
    const float* W2     = (const float*)d_in[9];
    const float* b2     = (const float*)d_in[10];
    float* out = (float*)d_out;

    int N = in_sizes[0];
    int E = in_sizes[3] / 2;
    const int* src = edge;
    const int* dst = edge + E;

    int*   ws    = (int*)d_ws;
    float* dinv  = (float*)(ws + OFF_DINV);
    int*   rowp  = ws + OFF_ROWP;
    int*   col   = ws + OFF_COL;
    int*   gfill = ws + OFF_GFILL;
    int*   gbase = ws + OFF_GBASE;
    unsigned int* scr = (unsigned int*)(ws + OFF_SCR);
    unsigned short* hb = (unsigned short*)(ws + OFF_H);
    unsigned int*   yb = (unsigned int*)(ws + OFF_Y);
    float* Pcat = (float*)(ws + OFF_PCAT);
    float* Psub = (float*)(ws + OFF_PSUB);

    hipMemsetAsync(gfill, 0, NBUCK * sizeof(int), stream);

    // small-table premultiplies (independent of CSR build)
    k_ptab<<<125, 256, 0, stream>>>(cat_t, W1,            Pcat, 1000);
    k_ptab<<<625, 256, 0, stream>>>(sub_t, W1 + 64 * 128, Psub, 5000);

    // CSR build: bin -> scan -> in-bucket sort (emits rowp, col, dinv)
    k_bin<<<200, 1024, 0, stream>>>(src, dst, E, gfill, scr);
    k_bscan<<<1, 256, 0, stream>>>(gfill, gbase, rowp, E);
    k_csr<<<NBUCK, 512, 0, stream>>>(scr, gfill, gbase, N, rowp, col, dinv);

    k_gemm1<<<(N + 63) / 64, 256, 0, stream>>>(cid, sid, eid, elem_t, W1, Pcat, Psub, dinv, hb, N);
    int aggblk = (N + 7) / 8;              // 2 nodes per wave, 4 waves per block
    k_agg1<<<aggblk, 256, 0, stream>>>(hb, rowp, col, dinv, b1, yb, N);
    k_gemm2<<<(N + 127) / 128, 256, 0, stream>>>(yb, W2, dinv, hb, N);
    k_agg2<<<aggblk, 256, 0, stream>>>(hb, rowp, col, dinv, b2, out, N);
}